// Round 1
// baseline (1771.848 us; speedup 1.0000x reference)
//
#include <hip/hip_runtime.h>
#include <math.h>

typedef float f32x4 __attribute__((ext_vector_type(4)));
typedef __bf16 bf16x8 __attribute__((ext_vector_type(8)));
typedef unsigned short u16x8 __attribute__((ext_vector_type(8)));

__device__ __forceinline__ unsigned short f2bf(float f) {
    union { float f; unsigned int u; } v; v.f = f;
    unsigned int r = v.u + 0x7FFFu + ((v.u >> 16) & 1u);
    return (unsigned short)(r >> 16);
}
__device__ __forceinline__ float bf2f(unsigned short u) {
    union { unsigned int u; float f; } v; v.u = ((unsigned int)u) << 16;
    return v.f;
}
__device__ __forceinline__ bf16x8 ld8(const unsigned short* p) {
    union { u16x8 u; bf16x8 b; } c;
    c.u = *(const u16x8*)p;
    return c.b;
}

// ---------------------------------------------------------------------------
// Weight transpose + fp32->bf16 convert: W[K][N] -> Wt[N][K]
// grid (N/32, K/32), block 256
__global__ __launch_bounds__(256)
void transpose_convert(const float* __restrict__ W, unsigned short* __restrict__ Wt,
                       int K, int N) {
    __shared__ float tile[32][33];
    int n0 = blockIdx.x * 32, k0 = blockIdx.y * 32;
    int tx = threadIdx.x & 31, ty = threadIdx.x >> 5;  // ty 0..7
#pragma unroll
    for (int i = 0; i < 4; ++i) {
        int k = ty + i * 8;
        tile[k][tx] = W[(size_t)(k0 + k) * N + n0 + tx];
    }
    __syncthreads();
#pragma unroll
    for (int i = 0; i < 4; ++i) {
        int n = ty + i * 8;
        Wt[(size_t)(n0 + n) * K + k0 + tx] = f2bf(tile[tx][n]);
    }
}

// ---------------------------------------------------------------------------
// x + positional encoding -> h (fp32) and hb (bf16)
__global__ __launch_bounds__(256)
void posenc_k(const float* __restrict__ x, float* __restrict__ h,
              unsigned short* __restrict__ hb) {
    int idx = blockIdx.x * 256 + threadIdx.x;
    const int TOT = 4 * 1024 * 768;
    if (idx >= TOT) return;
    int d = idx % 768;
    int s = (idx / 768) % 1024;
    int i2 = d >> 1;
    float dv = expf(-(float)(2 * i2) * (9.210340371976184f / 768.0f));
    float ang = (float)s * dv;
    float pe = (d & 1) ? cosf(ang) : sinf(ang);
    float v = x[idx] + pe;
    h[idx] = v;
    hb[idx] = f2bf(v);
}

// ---------------------------------------------------------------------------
// GEMM: C[M,N] = A[M,K](bf16) @ Bt[N,K](bf16)^T + bias, optional ReLU.
// 128x128 tile, BK=32, 256 threads = 4 waves (2x2), each wave 64x64 (4x4 MFMA).
#define LDSK 40

template<int WF32, int WBF16, int RELU>
__global__ __launch_bounds__(256)
void gemm_k(const unsigned short* __restrict__ A, const unsigned short* __restrict__ Bt,
            const float* __restrict__ bias, float* __restrict__ Cf,
            unsigned short* __restrict__ Cb, int M, int N, int K) {
    __shared__ unsigned short As[128 * LDSK];
    __shared__ unsigned short Bs[128 * LDSK];
    const int tid = threadIdx.x;
    const int lane = tid & 63, wave = tid >> 6;
    const int l15 = lane & 15, quad = lane >> 4;
    const int m0 = blockIdx.y * 128, n0 = blockIdx.x * 128;
    const int wr = (wave >> 1) * 64, wc = (wave & 1) * 64;

    const int sr = tid >> 1;
    const int sk = (tid & 1) * 16;
    const unsigned short* Ag = A + (size_t)(m0 + sr) * K + sk;
    const unsigned short* Bg = Bt + (size_t)(n0 + sr) * K + sk;

    f32x4 acc[4][4];
#pragma unroll
    for (int i = 0; i < 4; ++i)
#pragma unroll
        for (int j = 0; j < 4; ++j) acc[i][j] = (f32x4){0.f, 0.f, 0.f, 0.f};

    for (int k0 = 0; k0 < K; k0 += 32) {
        __syncthreads();
        *(u16x8*)&As[sr * LDSK + sk]     = *(const u16x8*)(Ag + k0);
        *(u16x8*)&As[sr * LDSK + sk + 8] = *(const u16x8*)(Ag + k0 + 8);
        *(u16x8*)&Bs[sr * LDSK + sk]     = *(const u16x8*)(Bg + k0);
        *(u16x8*)&Bs[sr * LDSK + sk + 8] = *(const u16x8*)(Bg + k0 + 8);
        __syncthreads();
        bf16x8 af[4], bfr[4];
#pragma unroll
        for (int mt = 0; mt < 4; ++mt)
            af[mt] = ld8(&As[(wr + mt * 16 + l15) * LDSK + quad * 8]);
#pragma unroll
        for (int nt = 0; nt < 4; ++nt)
            bfr[nt] = ld8(&Bs[(wc + nt * 16 + l15) * LDSK + quad * 8]);
#pragma unroll
        for (int mt = 0; mt < 4; ++mt)
#pragma unroll
            for (int nt = 0; nt < 4; ++nt)
                acc[mt][nt] = __builtin_amdgcn_mfma_f32_16x16x32_bf16(
                    af[mt], bfr[nt], acc[mt][nt], 0, 0, 0);
    }
#pragma unroll
    for (int mt = 0; mt < 4; ++mt)
#pragma unroll
        for (int nt = 0; nt < 4; ++nt)
#pragma unroll
            for (int r = 0; r < 4; ++r) {
                int row = m0 + wr + mt * 16 + quad * 4 + r;
                int col = n0 + wc + nt * 16 + l15;
                float v = acc[mt][nt][r] + bias[col];
                if (RELU) v = fmaxf(v, 0.f);
                if (WF32) Cf[(size_t)row * N + col] = v;
                if (WBF16) Cb[(size_t)row * N + col] = f2bf(v);
            }
}

// ---------------------------------------------------------------------------
// Split qkv (bf16 [4096, 2304], col = which*768 + h*64 + d) into
// Q (scaled by 0.125) and K, both [B,H,S,64] bf16. Vectorized by 8.
__global__ __launch_bounds__(256)
void qksplit_k(const unsigned short* __restrict__ qkv, unsigned short* __restrict__ Q,
               unsigned short* __restrict__ Ko) {
    int o8 = blockIdx.x * 256 + threadIdx.x;  // 0 .. 2*393216-1
    const int NQ8 = 393216;
    int which = (o8 >= NQ8) ? 1 : 0;
    int oo = o8 - which * NQ8;
    int dg = (oo & 7) * 8;
    int s = (oo >> 3) & 1023;
    int bh = oo >> 13;  // 0..47
    int h = bh % 12, b = bh / 12;
    size_t row = (size_t)(b * 1024 + s);
    int col = which * 768 + h * 64 + dg;
    u16x8 val = *(const u16x8*)&qkv[row * 2304 + col];
    if (!which) {
#pragma unroll
        for (int j = 0; j < 8; ++j) val[j] = f2bf(bf2f(val[j]) * 0.125f);
        *(u16x8*)&Q[((size_t)bh * 1024 + s) * 64 + dg] = val;
    } else {
        *(u16x8*)&Ko[((size_t)bh * 1024 + s) * 64 + dg] = val;
    }
}

// V transpose: qkv v-part -> Vt[B,H,64(d),1024(s)] bf16. grid (S/64, B*H)
__global__ __launch_bounds__(256)
void vt_k(const unsigned short* __restrict__ qkv, unsigned short* __restrict__ Vt) {
    __shared__ unsigned short t[64][65];
    int bh = blockIdx.y, s0 = blockIdx.x * 64;
    int b = bh / 12, h = bh % 12;
    int tx = threadIdx.x & 63;
    int ty = threadIdx.x >> 6;  // 0..3
#pragma unroll
    for (int r = 0; r < 16; ++r) {
        int i = ty + r * 4;
        t[i][tx] = qkv[(size_t)(b * 1024 + s0 + i) * 2304 + 1536 + h * 64 + tx];
    }
    __syncthreads();
#pragma unroll
    for (int r = 0; r < 16; ++r) {
        int dd = ty + r * 4;
        Vt[((size_t)bh * 64 + dd) * 1024 + s0 + tx] = t[tx][dd];
    }
}

// ---------------------------------------------------------------------------
// Flash attention: Q,K [B,H,S,64] bf16 (Q pre-scaled), Vt [B,H,64,S] bf16.
// Output ctx [B*S, 768] bf16 (already transposed back to (b,s,h*64+d)).
// grid (S/64, B*H), 256 threads = 4 waves; wave w handles q rows w*16..w*16+15.
__global__ __launch_bounds__(256)
void flash_k(const unsigned short* __restrict__ Q, const unsigned short* __restrict__ K,
             const unsigned short* __restrict__ Vt, unsigned short* __restrict__ ctx) {
    const int S = 1024, HD = 64;
    int bh = blockIdx.y;
    int b = bh / 12, h = bh % 12;
    int q0 = blockIdx.x * 64;
    const unsigned short* Qp = Q + ((size_t)bh * S + q0) * HD;
    const unsigned short* Kp = K + (size_t)bh * S * HD;
    const unsigned short* Vp = Vt + (size_t)bh * HD * S;

    __shared__ unsigned short Qs[64 * 72];
    __shared__ unsigned short Ks[64 * 72];
    __shared__ unsigned short Vs[64 * 72];
    __shared__ unsigned short Ps[4 * 16 * 72];

    int tid = threadIdx.x;
    int lane = tid & 63, wave = tid >> 6;
    int l15 = lane & 15, quad = lane >> 4;

    {
        int r = tid >> 2, koff = (tid & 3) * 16;
        *(u16x8*)&Qs[r * 72 + koff]     = *(const u16x8*)&Qp[r * HD + koff];
        *(u16x8*)&Qs[r * 72 + koff + 8] = *(const u16x8*)&Qp[r * HD + koff + 8];
    }

    f32x4 o[4];
#pragma unroll
    for (int i = 0; i < 4; ++i) o[i] = (f32x4){0.f, 0.f, 0.f, 0.f};
    float mprev[4] = {-INFINITY, -INFINITY, -INFINITY, -INFINITY};
    float lsum[4] = {0.f, 0.f, 0.f, 0.f};

    unsigned short* Pw = &Ps[wave * 16 * 72];

    for (int kt = 0; kt < 16; ++kt) {
        __syncthreads();
        {
            int r = tid >> 2, koff = (tid & 3) * 16;
            *(u16x8*)&Ks[r * 72 + koff]     = *(const u16x8*)&Kp[(kt * 64 + r) * HD + koff];
            *(u16x8*)&Ks[r * 72 + koff + 8] = *(const u16x8*)&Kp[(kt * 64 + r) * HD + koff + 8];
            *(u16x8*)&Vs[r * 72 + koff]     = *(const u16x8*)&Vp[r * S + kt * 64 + koff];
            *(u16x8*)&Vs[r * 72 + koff + 8] = *(const u16x8*)&Vp[r * S + kt * 64 + koff + 8];
        }
        __syncthreads();

        bf16x8 qa0 = ld8(&Qs[(wave * 16 + l15) * 72 + quad * 8]);
        bf16x8 qa1 = ld8(&Qs[(wave * 16 + l15) * 72 + 32 + quad * 8]);
        f32x4 sc[4];
#pragma unroll
        for (int cb = 0; cb < 4; ++cb) {
            bf16x8 kb0 = ld8(&Ks[(cb * 16 + l15) * 72 + quad * 8]);
            bf16x8 kb1 = ld8(&Ks[(cb * 16 + l15) * 72 + 32 + quad * 8]);
            f32x4 z = (f32x4){0.f, 0.f, 0.f, 0.f};
            z = __builtin_amdgcn_mfma_f32_16x16x32_bf16(qa0, kb0, z, 0, 0, 0);
            z = __builtin_amdgcn_mfma_f32_16x16x32_bf16(qa1, kb1, z, 0, 0, 0);
            sc[cb] = z;
        }
        float mnew[4], alpha[4];
#pragma unroll
        for (int r = 0; r < 4; ++r) {
            float m = fmaxf(fmaxf(sc[0][r], sc[1][r]), fmaxf(sc[2][r], sc[3][r]));
#pragma unroll
            for (int off = 1; off < 16; off <<= 1) m = fmaxf(m, __shfl_xor(m, off));
            float mn = fmaxf(mprev[r], m);
            alpha[r] = __expf(mprev[r] - mn);
            mnew[r] = mn;
        }
        float rsum[4] = {0.f, 0.f, 0.f, 0.f};
#pragma unroll
        for (int cb = 0; cb < 4; ++cb)
#pragma unroll
            for (int r = 0; r < 4; ++r) {
                float pv = __expf(sc[cb][r] - mnew[r]);
                sc[cb][r] = pv;
                rsum[r] += pv;
            }
#pragma unroll
        for (int r = 0; r < 4; ++r) {
#pragma unroll
            for (int off = 1; off < 16; off <<= 1) rsum[r] += __shfl_xor(rsum[r], off);
            lsum[r] = lsum[r] * alpha[r] + rsum[r];
            mprev[r] = mnew[r];
        }
#pragma unroll
        for (int cb = 0; cb < 4; ++cb)
#pragma unroll
            for (int r = 0; r < 4; ++r) o[cb][r] *= alpha[r];
        // P (C-layout) -> LDS -> A-operand layout
#pragma unroll
        for (int cb = 0; cb < 4; ++cb)
#pragma unroll
            for (int r = 0; r < 4; ++r)
                Pw[(quad * 4 + r) * 72 + cb * 16 + l15] = f2bf(sc[cb][r]);
        __syncthreads();
        bf16x8 pa0 = ld8(&Pw[l15 * 72 + quad * 8]);
        bf16x8 pa1 = ld8(&Pw[l15 * 72 + 32 + quad * 8]);
#pragma unroll
        for (int cb = 0; cb < 4; ++cb) {
            bf16x8 vb0 = ld8(&Vs[(cb * 16 + l15) * 72 + quad * 8]);
            bf16x8 vb1 = ld8(&Vs[(cb * 16 + l15) * 72 + 32 + quad * 8]);
            o[cb] = __builtin_amdgcn_mfma_f32_16x16x32_bf16(pa0, vb0, o[cb], 0, 0, 0);
            o[cb] = __builtin_amdgcn_mfma_f32_16x16x32_bf16(pa1, vb1, o[cb], 0, 0, 0);
        }
    }
#pragma unroll
    for (int cb = 0; cb < 4; ++cb)
#pragma unroll
        for (int r = 0; r < 4; ++r) {
            int row = q0 + wave * 16 + quad * 4 + r;
            float val = o[cb][r] / lsum[r];
            ctx[((size_t)(b * 1024 + row)) * 768 + h * 64 + cb * 16 + l15] = f2bf(val);
        }
}

// ---------------------------------------------------------------------------
// LayerNorm over D=768, optional residual add, writes fp32 (+ optional bf16).
template<int ADD_RES, int WBF16>
__global__ __launch_bounds__(256)
void ln_k(const float* __restrict__ X, const float* __restrict__ Res,
          const float* __restrict__ g, const float* __restrict__ bta,
          float* __restrict__ Yf, unsigned short* __restrict__ Yb) {
    const int D = 768;
    int row = blockIdx.x;
    int tid = threadIdx.x;
    const float* x = X + (size_t)row * D;
    float v[3];
    float s = 0.f, s2 = 0.f;
#pragma unroll
    for (int i = 0; i < 3; ++i) {
        int c = i * 256 + tid;
        float t = x[c];
        if (ADD_RES) t += Res[(size_t)row * D + c];
        v[i] = t;
        s += t;
        s2 += t * t;
    }
#pragma unroll
    for (int off = 1; off < 64; off <<= 1) {
        s += __shfl_xor(s, off);
        s2 += __shfl_xor(s2, off);
    }
    __shared__ float rs[4], rs2[4];
    int wave = tid >> 6, lane = tid & 63;
    if (lane == 0) { rs[wave] = s; rs2[wave] = s2; }
    __syncthreads();
    s = rs[0] + rs[1] + rs[2] + rs[3];
    s2 = rs2[0] + rs2[1] + rs2[2] + rs2[3];
    float mu = s * (1.f / 768.f);
    float var = s2 * (1.f / 768.f) - mu * mu;
    float rstd = rsqrtf(var + 1e-5f);
#pragma unroll
    for (int i = 0; i < 3; ++i) {
        int c = i * 256 + tid;
        float y = (v[i] - mu) * rstd * g[c] + bta[c];
        Yf[(size_t)row * D + c] = y;
        if (WBF16) Yb[(size_t)row * D + c] = f2bf(y);
    }
}

// ---------------------------------------------------------------------------
extern "C" void kernel_launch(void* const* d_in, const int* in_sizes, int n_in,
                              void* d_out, int out_size, void* d_ws, size_t ws_size,
                              hipStream_t stream) {
    const float* x    = (const float*)d_in[0];
    const float* Wqkv = (const float*)d_in[1];
    const float* bqkv = (const float*)d_in[2];
    const float* Wo   = (const float*)d_in[3];
    const float* bo   = (const float*)d_in[4];
    const float* ln1g = (const float*)d_in[5];
    const float* ln1b = (const float*)d_in[6];
    const float* W1   = (const float*)d_in[7];
    const float* b1   = (const float*)d_in[8];
    const float* W2   = (const float*)d_in[9];
    const float* b2   = (const float*)d_in[10];
    const float* ln2g = (const float*)d_in[11];
    const float* ln2b = (const float*)d_in[12];
    const float* lnfg = (const float*)d_in[13];
    const float* lnfb = (const float*)d_in[14];

    const int B = 4, S = 1024, D = 768, H = 12, F = 3072, L = 6;
    const int M = B * S;  // 4096

    char* p = (char*)d_ws;
    auto alloc = [&](size_t bytes) -> char* {
        char* r = p;
        p += (bytes + 255) & ~(size_t)255;
        return r;
    };
    float* h             = (float*)alloc((size_t)M * D * 4);
    float* tmp           = (float*)alloc((size_t)M * D * 4);
    unsigned short* hb   = (unsigned short*)alloc((size_t)M * D * 2);
    unsigned short* qkvb = (unsigned short*)alloc((size_t)M * 3 * D * 2);
    unsigned short* Qb   = (unsigned short*)alloc((size_t)M * D * 2);
    unsigned short* Kb   = (unsigned short*)alloc((size_t)M * D * 2);
    unsigned short* Vtb  = (unsigned short*)alloc((size_t)M * D * 2);
    unsigned short* ctx  = (unsigned short*)alloc((size_t)M * D * 2);
    unsigned short* f1b  = (unsigned short*)alloc((size_t)M * F * 2);
    unsigned short* wqkvT = (unsigned short*)alloc((size_t)L * 3 * D * D * 2);
    unsigned short* woT   = (unsigned short*)alloc((size_t)L * D * D * 2);
    unsigned short* w1T   = (unsigned short*)alloc((size_t)L * D * F * 2);
    unsigned short* w2T   = (unsigned short*)alloc((size_t)L * D * F * 2);

    for (int l = 0; l < L; ++l) {
        transpose_convert<<<dim3(3 * D / 32, D / 32), 256, 0, stream>>>(
            Wqkv + (size_t)l * D * 3 * D, wqkvT + (size_t)l * 3 * D * D, D, 3 * D);
        transpose_convert<<<dim3(D / 32, D / 32), 256, 0, stream>>>(
            Wo + (size_t)l * D * D, woT + (size_t)l * D * D, D, D);
        transpose_convert<<<dim3(F / 32, D / 32), 256, 0, stream>>>(
            W1 + (size_t)l * D * F, w1T + (size_t)l * D * F, D, F);
        transpose_convert<<<dim3(D / 32, F / 32), 256, 0, stream>>>(
            W2 + (size_t)l * F * D, w2T + (size_t)l * F * D, F, D);
    }
    posenc_k<<<(M * D) / 256, 256, 0, stream>>>(x, h, hb);

    for (int l = 0; l < L; ++l) {
        // qkv = h @ Wqkv + bqkv  (bf16 out)
        gemm_k<0, 1, 0><<<dim3(3 * D / 128, M / 128), 256, 0, stream>>>(
            hb, wqkvT + (size_t)l * 3 * D * D, bqkv + (size_t)l * 3 * D,
            nullptr, qkvb, M, 3 * D, D);
        qksplit_k<<<786432 / 256, 256, 0, stream>>>(qkvb, Qb, Kb);
        vt_k<<<dim3(S / 64, B * H), 256, 0, stream>>>(qkvb, Vtb);
        flash_k<<<dim3(S / 64, B * H), 256, 0, stream>>>(Qb, Kb, Vtb, ctx);
        // attn out proj (fp32 out)
        gemm_k<1, 0, 0><<<dim3(D / 128, M / 128), 256, 0, stream>>>(
            ctx, woT + (size_t)l * D * D, bo + (size_t)l * D, tmp, nullptr, M, D, D);
        ln_k<1, 1><<<M, 256, 0, stream>>>(h, tmp, ln1g + (size_t)l * D,
                                          ln1b + (size_t)l * D, h, hb);
        // ffn1 (relu, bf16 out)
        gemm_k<0, 1, 1><<<dim3(F / 128, M / 128), 256, 0, stream>>>(
            hb, w1T + (size_t)l * D * F, b1 + (size_t)l * F, nullptr, f1b, M, F, D);
        // ffn2 (fp32 out)
        gemm_k<1, 0, 0><<<dim3(D / 128, M / 128), 256, 0, stream>>>(
            f1b, w2T + (size_t)l * D * F, b2 + (size_t)l * D, tmp, nullptr, M, D, F);
        ln_k<1, 1><<<M, 256, 0, stream>>>(h, tmp, ln2g + (size_t)l * D,
                                          ln2b + (size_t)l * D, h, hb);
    }
    ln_k<0, 0><<<M, 256, 0, stream>>>(h, nullptr, lnfg, lnfb, (float*)d_out, nullptr);
}

// Round 2
// 1669.709 us; speedup vs baseline: 1.0612x; 1.0612x over previous
//
#include <hip/hip_runtime.h>
#include <math.h>

typedef float f32x4 __attribute__((ext_vector_type(4)));
typedef __bf16 bf16x8 __attribute__((ext_vector_type(8)));
typedef unsigned short u16x8 __attribute__((ext_vector_type(8)));

__device__ __forceinline__ unsigned short f2bf(float f) {
    union { float f; unsigned int u; } v; v.f = f;
    unsigned int r = v.u + 0x7FFFu + ((v.u >> 16) & 1u);
    return (unsigned short)(r >> 16);
}
__device__ __forceinline__ float bf2f(unsigned short u) {
    union { unsigned int u; float f; } v; v.u = ((unsigned int)u) << 16;
    return v.f;
}
__device__ __forceinline__ bf16x8 ld8(const unsigned short* p) {
    union { u16x8 u; bf16x8 b; } c;
    c.u = *(const u16x8*)p;
    return c.b;
}
// async global->LDS, 16B per lane; LDS dest = wave-uniform base + lane*16
__device__ __forceinline__ void gload_lds16(const unsigned short* g, unsigned short* l) {
    __builtin_amdgcn_global_load_lds(
        (const __attribute__((address_space(1))) unsigned int*)g,
        (__attribute__((address_space(3))) unsigned int*)l,
        16, 0, 0);
}

// ---------------------------------------------------------------------------
// Weight transpose + fp32->bf16 convert: W[K][N] -> Wt[N][K]
__global__ __launch_bounds__(256)
void transpose_convert(const float* __restrict__ W, unsigned short* __restrict__ Wt,
                       int K, int N) {
    __shared__ float tile[32][33];
    int n0 = blockIdx.x * 32, k0 = blockIdx.y * 32;
    int tx = threadIdx.x & 31, ty = threadIdx.x >> 5;
#pragma unroll
    for (int i = 0; i < 4; ++i) {
        int k = ty + i * 8;
        tile[k][tx] = W[(size_t)(k0 + k) * N + n0 + tx];
    }
    __syncthreads();
#pragma unroll
    for (int i = 0; i < 4; ++i) {
        int n = ty + i * 8;
        Wt[(size_t)(n0 + n) * K + k0 + tx] = f2bf(tile[tx][n]);
    }
}

// ---------------------------------------------------------------------------
__global__ __launch_bounds__(256)
void posenc_k(const float* __restrict__ x, float* __restrict__ h,
              unsigned short* __restrict__ hb) {
    int idx = blockIdx.x * 256 + threadIdx.x;
    const int TOT = 4 * 1024 * 768;
    if (idx >= TOT) return;
    int d = idx % 768;
    int s = (idx / 768) % 1024;
    int i2 = d >> 1;
    float dv = expf(-(float)(2 * i2) * (9.210340371976184f / 768.0f));
    float ang = (float)s * dv;
    float pe = (d & 1) ? cosf(ang) : sinf(ang);
    float v = x[idx] + pe;
    h[idx] = v;
    hb[idx] = f2bf(v);
}

// ---------------------------------------------------------------------------
// GEMM: C[M,N] = A[M,K](bf16) @ Bt[N,K](bf16)^T + bias, optional ReLU.
// 128x128 tile, BK=32, 256 threads = 4 waves (2x2), each wave 64x64 (4x4 MFMA).
// Staging via global_load_lds width=16 into unpadded [128][32] LDS with XOR
// swizzle kc_phys = kc_log ^ ((row>>1)&3) -> 2-way max bank aliasing (free).
__device__ __forceinline__ int swz_off(int row, int quad) {
    return row * 32 + ((quad ^ ((row >> 1) & 3)) << 3);
}

template<int WF32, int WBF16, int RELU>
__global__ __launch_bounds__(256)
void gemm_k(const unsigned short* __restrict__ A, const unsigned short* __restrict__ Bt,
            const float* __restrict__ bias, float* __restrict__ Cf,
            unsigned short* __restrict__ Cb, int M, int N, int K) {
    __shared__ unsigned short As[128 * 32];
    __shared__ unsigned short Bs[128 * 32];
    const int tid = threadIdx.x;
    const int lane = tid & 63, wave = tid >> 6;
    const int l15 = lane & 15, quad = lane >> 4;
    const int m0 = blockIdx.y * 128, n0 = blockIdx.x * 128;
    const int wr = (wave >> 1) * 64, wc = (wave & 1) * 64;

    // staging geometry: one wave-instr = 64 lanes * 16B = 16 rows of 64B.
    // wave stages rows [wave*32, wave*32+32) of both tiles (2 instrs each).
    const int r0 = wave * 32 + (lane >> 2);       // j=0 row; j=1 adds 16
    const int kc0 = lane & 3;

    f32x4 acc[4][4];
#pragma unroll
    for (int i = 0; i < 4; ++i)
#pragma unroll
        for (int j = 0; j < 4; ++j) acc[i][j] = (f32x4){0.f, 0.f, 0.f, 0.f};

    for (int k0 = 0; k0 < K; k0 += 32) {
        __syncthreads();
#pragma unroll
        for (int j = 0; j < 2; ++j) {
            int r = r0 + j * 16;
            int kcl = kc0 ^ ((r >> 1) & 3);
            const unsigned short* ga = A + (size_t)(m0 + r) * K + k0 + kcl * 8;
            const unsigned short* gb = Bt + (size_t)(n0 + r) * K + k0 + kcl * 8;
            unsigned short* la = &As[(wave * 32 + j * 16) * 32];
            unsigned short* lb = &Bs[(wave * 32 + j * 16) * 32];
            gload_lds16(ga, la);
            gload_lds16(gb, lb);
        }
        __syncthreads();
        bf16x8 af[4], bfr[4];
#pragma unroll
        for (int mt = 0; mt < 4; ++mt)
            af[mt] = ld8(&As[swz_off(wr + mt * 16 + l15, quad)]);
#pragma unroll
        for (int nt = 0; nt < 4; ++nt)
            bfr[nt] = ld8(&Bs[swz_off(wc + nt * 16 + l15, quad)]);
#pragma unroll
        for (int mt = 0; mt < 4; ++mt)
#pragma unroll
            for (int nt = 0; nt < 4; ++nt)
                acc[mt][nt] = __builtin_amdgcn_mfma_f32_16x16x32_bf16(
                    af[mt], bfr[nt], acc[mt][nt], 0, 0, 0);
    }
#pragma unroll
    for (int mt = 0; mt < 4; ++mt)
#pragma unroll
        for (int nt = 0; nt < 4; ++nt)
#pragma unroll
            for (int r = 0; r < 4; ++r) {
                int row = m0 + wr + mt * 16 + quad * 4 + r;
                int col = n0 + wc + nt * 16 + l15;
                float v = acc[mt][nt][r] + bias[col];
                if (RELU) v = fmaxf(v, 0.f);
                if (WF32) Cf[(size_t)row * N + col] = v;
                if (WBF16) Cb[(size_t)row * N + col] = f2bf(v);
            }
}

// ---------------------------------------------------------------------------
// Split qkv (bf16 [4096, 2304]) into Q (scaled 0.125) and K, [B,H,S,64] bf16.
__global__ __launch_bounds__(256)
void qksplit_k(const unsigned short* __restrict__ qkv, unsigned short* __restrict__ Q,
               unsigned short* __restrict__ Ko) {
    int o8 = blockIdx.x * 256 + threadIdx.x;
    const int NQ8 = 393216;
    int which = (o8 >= NQ8) ? 1 : 0;
    int oo = o8 - which * NQ8;
    int dg = (oo & 7) * 8;
    int s = (oo >> 3) & 1023;
    int bh = oo >> 13;
    int h = bh % 12, b = bh / 12;
    size_t row = (size_t)(b * 1024 + s);
    int col = which * 768 + h * 64 + dg;
    u16x8 val = *(const u16x8*)&qkv[row * 2304 + col];
    if (!which) {
#pragma unroll
        for (int j = 0; j < 8; ++j) val[j] = f2bf(bf2f(val[j]) * 0.125f);
        *(u16x8*)&Q[((size_t)bh * 1024 + s) * 64 + dg] = val;
    } else {
        *(u16x8*)&Ko[((size_t)bh * 1024 + s) * 64 + dg] = val;
    }
}

// V transpose: qkv v-part -> Vt[B,H,64(d),1024(s)] bf16. grid (S/64, B*H)
__global__ __launch_bounds__(256)
void vt_k(const unsigned short* __restrict__ qkv, unsigned short* __restrict__ Vt) {
    __shared__ unsigned short t[64][65];
    int bh = blockIdx.y, s0 = blockIdx.x * 64;
    int b = bh / 12, h = bh % 12;
    int tx = threadIdx.x & 63;
    int ty = threadIdx.x >> 6;
#pragma unroll
    for (int r = 0; r < 16; ++r) {
        int i = ty + r * 4;
        t[i][tx] = qkv[(size_t)(b * 1024 + s0 + i) * 2304 + 1536 + h * 64 + tx];
    }
    __syncthreads();
#pragma unroll
    for (int r = 0; r < 16; ++r) {
        int dd = ty + r * 4;
        Vt[((size_t)bh * 64 + dd) * 1024 + s0 + tx] = t[tx][dd];
    }
}

// ---------------------------------------------------------------------------
// Flash attention: Q,K [B,H,S,64] bf16 (Q pre-scaled), Vt [B,H,64,S] bf16.
// Output ctx [B*S, 768] bf16. grid (S/64, B*H), 256 threads = 4 waves.
__global__ __launch_bounds__(256)
void flash_k(const unsigned short* __restrict__ Q, const unsigned short* __restrict__ K,
             const unsigned short* __restrict__ Vt, unsigned short* __restrict__ ctx) {
    const int S = 1024, HD = 64;
    int bh = blockIdx.y;
    int b = bh / 12, h = bh % 12;
    int q0 = blockIdx.x * 64;
    const unsigned short* Qp = Q + ((size_t)bh * S + q0) * HD;
    const unsigned short* Kp = K + (size_t)bh * S * HD;
    const unsigned short* Vp = Vt + (size_t)bh * HD * S;

    __shared__ unsigned short Qs[64 * 72];
    __shared__ unsigned short Ks[64 * 72];
    __shared__ unsigned short Vs[64 * 72];
    __shared__ unsigned short Ps[4 * 16 * 72];

    int tid = threadIdx.x;
    int lane = tid & 63, wave = tid >> 6;
    int l15 = lane & 15, quad = lane >> 4;

    {
        int r = tid >> 2, koff = (tid & 3) * 16;
        *(u16x8*)&Qs[r * 72 + koff]     = *(const u16x8*)&Qp[r * HD + koff];
        *(u16x8*)&Qs[r * 72 + koff + 8] = *(const u16x8*)&Qp[r * HD + koff + 8];
    }

    f32x4 o[4];
#pragma unroll
    for (int i = 0; i < 4; ++i) o[i] = (f32x4){0.f, 0.f, 0.f, 0.f};
    float mprev[4] = {-INFINITY, -INFINITY, -INFINITY, -INFINITY};
    float lsum[4] = {0.f, 0.f, 0.f, 0.f};

    unsigned short* Pw = &Ps[wave * 16 * 72];

    for (int kt = 0; kt < 16; ++kt) {
        __syncthreads();
        {
            int r = tid >> 2, koff = (tid & 3) * 16;
            *(u16x8*)&Ks[r * 72 + koff]     = *(const u16x8*)&Kp[(kt * 64 + r) * HD + koff];
            *(u16x8*)&Ks[r * 72 + koff + 8] = *(const u16x8*)&Kp[(kt * 64 + r) * HD + koff + 8];
            *(u16x8*)&Vs[r * 72 + koff]     = *(const u16x8*)&Vp[r * S + kt * 64 + koff];
            *(u16x8*)&Vs[r * 72 + koff + 8] = *(const u16x8*)&Vp[r * S + kt * 64 + koff + 8];
        }
        __syncthreads();

        bf16x8 qa0 = ld8(&Qs[(wave * 16 + l15) * 72 + quad * 8]);
        bf16x8 qa1 = ld8(&Qs[(wave * 16 + l15) * 72 + 32 + quad * 8]);
        f32x4 sc[4];
#pragma unroll
        for (int cb = 0; cb < 4; ++cb) {
            bf16x8 kb0 = ld8(&Ks[(cb * 16 + l15) * 72 + quad * 8]);
            bf16x8 kb1 = ld8(&Ks[(cb * 16 + l15) * 72 + 32 + quad * 8]);
            f32x4 z = (f32x4){0.f, 0.f, 0.f, 0.f};
            z = __builtin_amdgcn_mfma_f32_16x16x32_bf16(qa0, kb0, z, 0, 0, 0);
            z = __builtin_amdgcn_mfma_f32_16x16x32_bf16(qa1, kb1, z, 0, 0, 0);
            sc[cb] = z;
        }
        float mnew[4], alpha[4];
#pragma unroll
        for (int r = 0; r < 4; ++r) {
            float m = fmaxf(fmaxf(sc[0][r], sc[1][r]), fmaxf(sc[2][r], sc[3][r]));
#pragma unroll
            for (int off = 1; off < 16; off <<= 1) m = fmaxf(m, __shfl_xor(m, off));
            float mn = fmaxf(mprev[r], m);
            alpha[r] = __expf(mprev[r] - mn);
            mnew[r] = mn;
        }
        float rsum[4] = {0.f, 0.f, 0.f, 0.f};
#pragma unroll
        for (int cb = 0; cb < 4; ++cb)
#pragma unroll
            for (int r = 0; r < 4; ++r) {
                float pv = __expf(sc[cb][r] - mnew[r]);
                sc[cb][r] = pv;
                rsum[r] += pv;
            }
#pragma unroll
        for (int r = 0; r < 4; ++r) {
#pragma unroll
            for (int off = 1; off < 16; off <<= 1) rsum[r] += __shfl_xor(rsum[r], off);
            lsum[r] = lsum[r] * alpha[r] + rsum[r];
            mprev[r] = mnew[r];
        }
#pragma unroll
        for (int cb = 0; cb < 4; ++cb)
#pragma unroll
            for (int r = 0; r < 4; ++r) o[cb][r] *= alpha[r];
#pragma unroll
        for (int cb = 0; cb < 4; ++cb)
#pragma unroll
            for (int r = 0; r < 4; ++r)
                Pw[(quad * 4 + r) * 72 + cb * 16 + l15] = f2bf(sc[cb][r]);
        __syncthreads();
        bf16x8 pa0 = ld8(&Pw[l15 * 72 + quad * 8]);
        bf16x8 pa1 = ld8(&Pw[l15 * 72 + 32 + quad * 8]);
#pragma unroll
        for (int cb = 0; cb < 4; ++cb) {
            bf16x8 vb0 = ld8(&Vs[(cb * 16 + l15) * 72 + quad * 8]);
            bf16x8 vb1 = ld8(&Vs[(cb * 16 + l15) * 72 + 32 + quad * 8]);
            o[cb] = __builtin_amdgcn_mfma_f32_16x16x32_bf16(pa0, vb0, o[cb], 0, 0, 0);
            o[cb] = __builtin_amdgcn_mfma_f32_16x16x32_bf16(pa1, vb1, o[cb], 0, 0, 0);
        }
    }
#pragma unroll
    for (int cb = 0; cb < 4; ++cb)
#pragma unroll
        for (int r = 0; r < 4; ++r) {
            int row = q0 + wave * 16 + quad * 4 + r;
            float val = o[cb][r] / lsum[r];
            ctx[((size_t)(b * 1024 + row)) * 768 + h * 64 + cb * 16 + l15] = f2bf(val);
        }
}

// ---------------------------------------------------------------------------
template<int ADD_RES, int WBF16>
__global__ __launch_bounds__(256)
void ln_k(const float* __restrict__ X, const float* __restrict__ Res,
          const float* __restrict__ g, const float* __restrict__ bta,
          float* __restrict__ Yf, unsigned short* __restrict__ Yb) {
    const int D = 768;
    int row = blockIdx.x;
    int tid = threadIdx.x;
    const float* x = X + (size_t)row * D;
    float v[3];
    float s = 0.f, s2 = 0.f;
#pragma unroll
    for (int i = 0; i < 3; ++i) {
        int c = i * 256 + tid;
        float t = x[c];
        if (ADD_RES) t += Res[(size_t)row * D + c];
        v[i] = t;
        s += t;
        s2 += t * t;
    }
#pragma unroll
    for (int off = 1; off < 64; off <<= 1) {
        s += __shfl_xor(s, off);
        s2 += __shfl_xor(s2, off);
    }
    __shared__ float rs[4], rs2[4];
    int wave = tid >> 6, lane = tid & 63;
    if (lane == 0) { rs[wave] = s; rs2[wave] = s2; }
    __syncthreads();
    s = rs[0] + rs[1] + rs[2] + rs[3];
    s2 = rs2[0] + rs2[1] + rs2[2] + rs2[3];
    float mu = s * (1.f / 768.f);
    float var = s2 * (1.f / 768.f) - mu * mu;
    float rstd = rsqrtf(var + 1e-5f);
#pragma unroll
    for (int i = 0; i < 3; ++i) {
        int c = i * 256 + tid;
        float y = (v[i] - mu) * rstd * g[c] + bta[c];
        Yf[(size_t)row * D + c] = y;
        if (WBF16) Yb[(size_t)row * D + c] = f2bf(y);
    }
}

// ---------------------------------------------------------------------------
extern "C" void kernel_launch(void* const* d_in, const int* in_sizes, int n_in,
                              void* d_out, int out_size, void* d_ws, size_t ws_size,
                              hipStream_t stream) {
    const float* x    = (const float*)d_in[0];
    const float* Wqkv = (const float*)d_in[1];
    const float* bqkv = (const float*)d_in[2];
    const float* Wo   = (const float*)d_in[3];
    const float* bo   = (const float*)d_in[4];
    const float* ln1g = (const float*)d_in[5];
    const float* ln1b = (const float*)d_in[6];
    const float* W1   = (const float*)d_in[7];
    const float* b1   = (const float*)d_in[8];
    const float* W2   = (const float*)d_in[9];
    const float* b2   = (const float*)d_in[10];
    const float* ln2g = (const float*)d_in[11];
    const float* ln2b = (const float*)d_in[12];
    const float* lnfg = (const float*)d_in[13];
    const float* lnfb = (const float*)d_in[14];

    const int B = 4, S = 1024, D = 768, H = 12, F = 3072, L = 6;
    const int M = B * S;  // 4096

    char* p = (char*)d_ws;
    auto alloc = [&](size_t bytes) -> char* {
        char* r = p;
        p += (bytes + 255) & ~(size_t)255;
        return r;
    };
    float* h             = (float*)alloc((size_t)M * D * 4);
    float* tmp           = (float*)alloc((size_t)M * D * 4);
    unsigned short* hb   = (unsigned short*)alloc((size_t)M * D * 2);
    unsigned short* qkvb = (unsigned short*)alloc((size_t)M * 3 * D * 2);
    unsigned short* Qb   = (unsigned short*)alloc((size_t)M * D * 2);
    unsigned short* Kb   = (unsigned short*)alloc((size_t)M * D * 2);
    unsigned short* Vtb  = (unsigned short*)alloc((size_t)M * D * 2);
    unsigned short* ctx  = (unsigned short*)alloc((size_t)M * D * 2);
    unsigned short* f1b  = (unsigned short*)alloc((size_t)M * F * 2);
    unsigned short* wqkvT = (unsigned short*)alloc((size_t)L * 3 * D * D * 2);
    unsigned short* woT   = (unsigned short*)alloc((size_t)L * D * D * 2);
    unsigned short* w1T   = (unsigned short*)alloc((size_t)L * D * F * 2);
    unsigned short* w2T   = (unsigned short*)alloc((size_t)L * D * F * 2);

    for (int l = 0; l < L; ++l) {
        transpose_convert<<<dim3(3 * D / 32, D / 32), 256, 0, stream>>>(
            Wqkv + (size_t)l * D * 3 * D, wqkvT + (size_t)l * 3 * D * D, D, 3 * D);
        transpose_convert<<<dim3(D / 32, D / 32), 256, 0, stream>>>(
            Wo + (size_t)l * D * D, woT + (size_t)l * D * D, D, D);
        transpose_convert<<<dim3(F / 32, D / 32), 256, 0, stream>>>(
            W1 + (size_t)l * D * F, w1T + (size_t)l * D * F, D, F);
        transpose_convert<<<dim3(D / 32, F / 32), 256, 0, stream>>>(
            W2 + (size_t)l * F * D, w2T + (size_t)l * F * D, F, D);
    }
    posenc_k<<<(M * D) / 256, 256, 0, stream>>>(x, h, hb);

    for (int l = 0; l < L; ++l) {
        gemm_k<0, 1, 0><<<dim3(3 * D / 128, M / 128), 256, 0, stream>>>(
            hb, wqkvT + (size_t)l * 3 * D * D, bqkv + (size_t)l * 3 * D,
            nullptr, qkvb, M, 3 * D, D);
        qksplit_k<<<786432 / 256, 256, 0, stream>>>(qkvb, Qb, Kb);
        vt_k<<<dim3(S / 64, B * H), 256, 0, stream>>>(qkvb, Vtb);
        flash_k<<<dim3(S / 64, B * H), 256, 0, stream>>>(Qb, Kb, Vtb, ctx);
        gemm_k<1, 0, 0><<<dim3(D / 128, M / 128), 256, 0, stream>>>(
            ctx, woT + (size_t)l * D * D, bo + (size_t)l * D, tmp, nullptr, M, D, D);
        ln_k<1, 1><<<M, 256, 0, stream>>>(h, tmp, ln1g + (size_t)l * D,
                                          ln1b + (size_t)l * D, h, hb);
        gemm_k<0, 1, 1><<<dim3(F / 128, M / 128), 256, 0, stream>>>(
            hb, w1T + (size_t)l * D * F, b1 + (size_t)l * F, nullptr, f1b, M, F, D);
        gemm_k<1, 0, 0><<<dim3(D / 128, M / 128), 256, 0, stream>>>(
            f1b, w2T + (size_t)l * D * F, b2 + (size_t)l * D, tmp, nullptr, M, D, F);
        ln_k<1, 1><<<M, 256, 0, stream>>>(h, tmp, ln2g + (size_t)l * D,
                                          ln2b + (size_t)l * D, h, hb);
    }
    ln_k<0, 0><<<M, 256, 0, stream>>>(h, nullptr, lnfg, lnfb, (float*)d_out, nullptr);
}

// Round 3
// 1476.379 us; speedup vs baseline: 1.2001x; 1.1309x over previous
//
#include <hip/hip_runtime.h>
#include <math.h>

typedef float f32x4 __attribute__((ext_vector_type(4)));
typedef __bf16 bf16x8 __attribute__((ext_vector_type(8)));
typedef unsigned short u16x8 __attribute__((ext_vector_type(8)));

__device__ __forceinline__ unsigned short f2bf(float f) {
    union { float f; unsigned int u; } v; v.f = f;
    unsigned int r = v.u + 0x7FFFu + ((v.u >> 16) & 1u);
    return (unsigned short)(r >> 16);
}
__device__ __forceinline__ float bf2f(unsigned short u) {
    union { unsigned int u; float f; } v; v.u = ((unsigned int)u) << 16;
    return v.f;
}
__device__ __forceinline__ bf16x8 ld8(const unsigned short* p) {
    union { u16x8 u; bf16x8 b; } c;
    c.u = *(const u16x8*)p;
    return c.b;
}
__device__ __forceinline__ void gload_lds16(const unsigned short* g, unsigned short* l) {
    __builtin_amdgcn_global_load_lds(
        (const __attribute__((address_space(1))) unsigned int*)g,
        (__attribute__((address_space(3))) unsigned int*)l,
        16, 0, 0);
}

// ---------------------------------------------------------------------------
// Weight transpose + fp32->bf16 convert: W[K][N] -> Wt[N][K]
__global__ __launch_bounds__(256)
void transpose_convert(const float* __restrict__ W, unsigned short* __restrict__ Wt,
                       int K, int N) {
    __shared__ float tile[32][33];
    int n0 = blockIdx.x * 32, k0 = blockIdx.y * 32;
    int tx = threadIdx.x & 31, ty = threadIdx.x >> 5;
#pragma unroll
    for (int i = 0; i < 4; ++i) {
        int k = ty + i * 8;
        tile[k][tx] = W[(size_t)(k0 + k) * N + n0 + tx];
    }
    __syncthreads();
#pragma unroll
    for (int i = 0; i < 4; ++i) {
        int n = ty + i * 8;
        Wt[(size_t)(n0 + n) * K + k0 + tx] = f2bf(tile[tx][n]);
    }
}

// ---------------------------------------------------------------------------
__global__ __launch_bounds__(256)
void posenc_k(const float* __restrict__ x, float* __restrict__ h,
              unsigned short* __restrict__ hb) {
    int idx = blockIdx.x * 256 + threadIdx.x;
    const int TOT = 4 * 1024 * 768;
    if (idx >= TOT) return;
    int d = idx % 768;
    int s = (idx / 768) % 1024;
    int i2 = d >> 1;
    float dv = expf(-(float)(2 * i2) * (9.210340371976184f / 768.0f));
    float ang = (float)s * dv;
    float pe = (d & 1) ? cosf(ang) : sinf(ang);
    float v = x[idx] + pe;
    h[idx] = v;
    hb[idx] = f2bf(v);
}

// ---------------------------------------------------------------------------
// GEMM: C[M,N] = A[M,K](bf16) @ Bt[N,K](bf16)^T (+bias) (+relu).
// 128x128 tile, BK=32, 256 threads = 4 waves, wave = 64x64 via 4x4 MFMA.
// global_load_lds width=16 staging; XOR swizzle kills bank conflicts.
// Split-K: blockIdx.z selects K-chunk [z*Kc, (z+1)*Kc), partial -> Cf + z*M*N.
__device__ __forceinline__ int swz_off(int row, int quad) {
    return row * 32 + ((quad ^ ((row >> 1) & 3)) << 3);
}

template<int WF32, int WBF16, int RELU, int BIAS>
__global__ __launch_bounds__(256)
void gemm_k(const unsigned short* __restrict__ A, const unsigned short* __restrict__ Bt,
            const float* __restrict__ bias, float* __restrict__ Cf,
            unsigned short* __restrict__ Cb, int M, int N, int K, int Kc) {
    __shared__ unsigned short As[128 * 32];
    __shared__ unsigned short Bs[128 * 32];
    const int tid = threadIdx.x;
    const int lane = tid & 63, wave = tid >> 6;
    const int l15 = lane & 15, quad = lane >> 4;
    const int m0 = blockIdx.y * 128, n0 = blockIdx.x * 128;
    const int wr = (wave >> 1) * 64, wc = (wave & 1) * 64;
    const int kstart = blockIdx.z * Kc, kend = kstart + Kc;
    float* Cfp = Cf + (size_t)blockIdx.z * M * N;

    const int r0 = wave * 32 + (lane >> 2);
    const int kc0 = lane & 3;

    f32x4 acc[4][4];
#pragma unroll
    for (int i = 0; i < 4; ++i)
#pragma unroll
        for (int j = 0; j < 4; ++j) acc[i][j] = (f32x4){0.f, 0.f, 0.f, 0.f};

    for (int k0 = kstart; k0 < kend; k0 += 32) {
        __syncthreads();
#pragma unroll
        for (int j = 0; j < 2; ++j) {
            int r = r0 + j * 16;
            int kcl = kc0 ^ ((r >> 1) & 3);
            const unsigned short* ga = A + (size_t)(m0 + r) * K + k0 + kcl * 8;
            const unsigned short* gb = Bt + (size_t)(n0 + r) * K + k0 + kcl * 8;
            unsigned short* la = &As[(wave * 32 + j * 16) * 32];
            unsigned short* lb = &Bs[(wave * 32 + j * 16) * 32];
            gload_lds16(ga, la);
            gload_lds16(gb, lb);
        }
        __syncthreads();
        bf16x8 af[4], bfr[4];
#pragma unroll
        for (int mt = 0; mt < 4; ++mt)
            af[mt] = ld8(&As[swz_off(wr + mt * 16 + l15, quad)]);
#pragma unroll
        for (int nt = 0; nt < 4; ++nt)
            bfr[nt] = ld8(&Bs[swz_off(wc + nt * 16 + l15, quad)]);
#pragma unroll
        for (int mt = 0; mt < 4; ++mt)
#pragma unroll
            for (int nt = 0; nt < 4; ++nt)
                acc[mt][nt] = __builtin_amdgcn_mfma_f32_16x16x32_bf16(
                    af[mt], bfr[nt], acc[mt][nt], 0, 0, 0);
    }
#pragma unroll
    for (int mt = 0; mt < 4; ++mt)
#pragma unroll
        for (int nt = 0; nt < 4; ++nt)
#pragma unroll
            for (int r = 0; r < 4; ++r) {
                int row = m0 + wr + mt * 16 + quad * 4 + r;
                int col = n0 + wc + nt * 16 + l15;
                float v = acc[mt][nt][r];
                if (BIAS) v += bias[col];
                if (RELU) v = fmaxf(v, 0.f);
                if (WF32) Cfp[(size_t)row * N + col] = v;
                if (WBF16) Cb[(size_t)row * N + col] = f2bf(v);
            }
}

// ---------------------------------------------------------------------------
// Split qkv (bf16 [4096, 2304]) into Q (scaled 0.125) and K, [B,H,S,64] bf16.
__global__ __launch_bounds__(256)
void qksplit_k(const unsigned short* __restrict__ qkv, unsigned short* __restrict__ Q,
               unsigned short* __restrict__ Ko) {
    int o8 = blockIdx.x * 256 + threadIdx.x;
    const int NQ8 = 393216;
    int which = (o8 >= NQ8) ? 1 : 0;
    int oo = o8 - which * NQ8;
    int dg = (oo & 7) * 8;
    int s = (oo >> 3) & 1023;
    int bh = oo >> 13;
    int h = bh % 12, b = bh / 12;
    size_t row = (size_t)(b * 1024 + s);
    int col = which * 768 + h * 64 + dg;
    u16x8 val = *(const u16x8*)&qkv[row * 2304 + col];
    if (!which) {
#pragma unroll
        for (int j = 0; j < 8; ++j) val[j] = f2bf(bf2f(val[j]) * 0.125f);
        *(u16x8*)&Q[((size_t)bh * 1024 + s) * 64 + dg] = val;
    } else {
        *(u16x8*)&Ko[((size_t)bh * 1024 + s) * 64 + dg] = val;
    }
}

// V transpose: qkv v-part -> Vt[B,H,64(d),1024(s)] bf16. grid (S/64, B*H)
__global__ __launch_bounds__(256)
void vt_k(const unsigned short* __restrict__ qkv, unsigned short* __restrict__ Vt) {
    __shared__ unsigned short t[64][65];
    int bh = blockIdx.y, s0 = blockIdx.x * 64;
    int b = bh / 12, h = bh % 12;
    int tx = threadIdx.x & 63;
    int ty = threadIdx.x >> 6;
#pragma unroll
    for (int r = 0; r < 16; ++r) {
        int i = ty + r * 4;
        t[i][tx] = qkv[(size_t)(b * 1024 + s0 + i) * 2304 + 1536 + h * 64 + tx];
    }
    __syncthreads();
#pragma unroll
    for (int r = 0; r < 16; ++r) {
        int dd = ty + r * 4;
        Vt[((size_t)bh * 64 + dd) * 1024 + s0 + tx] = t[tx][dd];
    }
}

// ---------------------------------------------------------------------------
// Flash attention: Q,K [B,H,S,64] bf16 (Q pre-scaled), Vt [B,H,64,S] bf16.
__global__ __launch_bounds__(256)
void flash_k(const unsigned short* __restrict__ Q, const unsigned short* __restrict__ K,
             const unsigned short* __restrict__ Vt, unsigned short* __restrict__ ctx) {
    const int S = 1024, HD = 64;
    int bh = blockIdx.y;
    int b = bh / 12, h = bh % 12;
    int q0 = blockIdx.x * 64;
    const unsigned short* Qp = Q + ((size_t)bh * S + q0) * HD;
    const unsigned short* Kp = K + (size_t)bh * S * HD;
    const unsigned short* Vp = Vt + (size_t)bh * HD * S;

    __shared__ unsigned short Qs[64 * 72];
    __shared__ unsigned short Ks[64 * 72];
    __shared__ unsigned short Vs[64 * 72];
    __shared__ unsigned short Ps[4 * 16 * 72];

    int tid = threadIdx.x;
    int lane = tid & 63, wave = tid >> 6;
    int l15 = lane & 15, quad = lane >> 4;

    {
        int r = tid >> 2, koff = (tid & 3) * 16;
        *(u16x8*)&Qs[r * 72 + koff]     = *(const u16x8*)&Qp[r * HD + koff];
        *(u16x8*)&Qs[r * 72 + koff + 8] = *(const u16x8*)&Qp[r * HD + koff + 8];
    }

    f32x4 o[4];
#pragma unroll
    for (int i = 0; i < 4; ++i) o[i] = (f32x4){0.f, 0.f, 0.f, 0.f};
    float mprev[4] = {-INFINITY, -INFINITY, -INFINITY, -INFINITY};
    float lsum[4] = {0.f, 0.f, 0.f, 0.f};

    unsigned short* Pw = &Ps[wave * 16 * 72];

    for (int kt = 0; kt < 16; ++kt) {
        __syncthreads();
        {
            int r = tid >> 2, koff = (tid & 3) * 16;
            *(u16x8*)&Ks[r * 72 + koff]     = *(const u16x8*)&Kp[(kt * 64 + r) * HD + koff];
            *(u16x8*)&Ks[r * 72 + koff + 8] = *(const u16x8*)&Kp[(kt * 64 + r) * HD + koff + 8];
            *(u16x8*)&Vs[r * 72 + koff]     = *(const u16x8*)&Vp[r * S + kt * 64 + koff];
            *(u16x8*)&Vs[r * 72 + koff + 8] = *(const u16x8*)&Vp[r * S + kt * 64 + koff + 8];
        }
        __syncthreads();

        bf16x8 qa0 = ld8(&Qs[(wave * 16 + l15) * 72 + quad * 8]);
        bf16x8 qa1 = ld8(&Qs[(wave * 16 + l15) * 72 + 32 + quad * 8]);
        f32x4 sc[4];
#pragma unroll
        for (int cb = 0; cb < 4; ++cb) {
            bf16x8 kb0 = ld8(&Ks[(cb * 16 + l15) * 72 + quad * 8]);
            bf16x8 kb1 = ld8(&Ks[(cb * 16 + l15) * 72 + 32 + quad * 8]);
            f32x4 z = (f32x4){0.f, 0.f, 0.f, 0.f};
            z = __builtin_amdgcn_mfma_f32_16x16x32_bf16(qa0, kb0, z, 0, 0, 0);
            z = __builtin_amdgcn_mfma_f32_16x16x32_bf16(qa1, kb1, z, 0, 0, 0);
            sc[cb] = z;
        }
        float mnew[4], alpha[4];
#pragma unroll
        for (int r = 0; r < 4; ++r) {
            float m = fmaxf(fmaxf(sc[0][r], sc[1][r]), fmaxf(sc[2][r], sc[3][r]));
#pragma unroll
            for (int off = 1; off < 16; off <<= 1) m = fmaxf(m, __shfl_xor(m, off));
            float mn = fmaxf(mprev[r], m);
            alpha[r] = __expf(mprev[r] - mn);
            mnew[r] = mn;
        }
        float rsum[4] = {0.f, 0.f, 0.f, 0.f};
#pragma unroll
        for (int cb = 0; cb < 4; ++cb)
#pragma unroll
            for (int r = 0; r < 4; ++r) {
                float pv = __expf(sc[cb][r] - mnew[r]);
                sc[cb][r] = pv;
                rsum[r] += pv;
            }
#pragma unroll
        for (int r = 0; r < 4; ++r) {
#pragma unroll
            for (int off = 1; off < 16; off <<= 1) rsum[r] += __shfl_xor(rsum[r], off);
            lsum[r] = lsum[r] * alpha[r] + rsum[r];
            mprev[r] = mnew[r];
        }
#pragma unroll
        for (int cb = 0; cb < 4; ++cb)
#pragma unroll
            for (int r = 0; r < 4; ++r) o[cb][r] *= alpha[r];
#pragma unroll
        for (int cb = 0; cb < 4; ++cb)
#pragma unroll
            for (int r = 0; r < 4; ++r)
                Pw[(quad * 4 + r) * 72 + cb * 16 + l15] = f2bf(sc[cb][r]);
        __syncthreads();
        bf16x8 pa0 = ld8(&Pw[l15 * 72 + quad * 8]);
        bf16x8 pa1 = ld8(&Pw[l15 * 72 + 32 + quad * 8]);
#pragma unroll
        for (int cb = 0; cb < 4; ++cb) {
            bf16x8 vb0 = ld8(&Vs[(cb * 16 + l15) * 72 + quad * 8]);
            bf16x8 vb1 = ld8(&Vs[(cb * 16 + l15) * 72 + 32 + quad * 8]);
            o[cb] = __builtin_amdgcn_mfma_f32_16x16x32_bf16(pa0, vb0, o[cb], 0, 0, 0);
            o[cb] = __builtin_amdgcn_mfma_f32_16x16x32_bf16(pa1, vb1, o[cb], 0, 0, 0);
        }
    }
#pragma unroll
    for (int cb = 0; cb < 4; ++cb)
#pragma unroll
        for (int r = 0; r < 4; ++r) {
            int row = q0 + wave * 16 + quad * 4 + r;
            float val = o[cb][r] / lsum[r];
            ctx[((size_t)(b * 1024 + row)) * 768 + h * 64 + cb * 16 + l15] = f2bf(val);
        }
}

// ---------------------------------------------------------------------------
// LayerNorm over D=768. NPART>0: residual = X + sum(partials) + proj-bias.
template<int NPART, int WBF16>
__global__ __launch_bounds__(256)
void ln_k(const float* __restrict__ X, const float* __restrict__ P,
          const float* __restrict__ pb,
          const float* __restrict__ g, const float* __restrict__ bta,
          float* __restrict__ Yf, unsigned short* __restrict__ Yb) {
    const int D = 768;
    const size_t MD = (size_t)4096 * 768;
    int row = blockIdx.x;
    int tid = threadIdx.x;
    const float* x = X + (size_t)row * D;
    float v[3];
    float s = 0.f, s2 = 0.f;
#pragma unroll
    for (int i = 0; i < 3; ++i) {
        int c = i * 256 + tid;
        float t = x[c];
        if (NPART > 0) {
            float r = pb[c];
#pragma unroll
            for (int pi = 0; pi < NPART; ++pi)
                r += P[MD * pi + (size_t)row * D + c];
            t += r;
        }
        v[i] = t;
        s += t;
        s2 += t * t;
    }
#pragma unroll
    for (int off = 1; off < 64; off <<= 1) {
        s += __shfl_xor(s, off);
        s2 += __shfl_xor(s2, off);
    }
    __shared__ float rs[4], rs2[4];
    int wave = tid >> 6, lane = tid & 63;
    if (lane == 0) { rs[wave] = s; rs2[wave] = s2; }
    __syncthreads();
    s = rs[0] + rs[1] + rs[2] + rs[3];
    s2 = rs2[0] + rs2[1] + rs2[2] + rs2[3];
    float mu = s * (1.f / 768.f);
    float var = s2 * (1.f / 768.f) - mu * mu;
    float rstd = rsqrtf(var + 1e-5f);
#pragma unroll
    for (int i = 0; i < 3; ++i) {
        int c = i * 256 + tid;
        float y = (v[i] - mu) * rstd * g[c] + bta[c];
        Yf[(size_t)row * D + c] = y;
        if (WBF16) Yb[(size_t)row * D + c] = f2bf(y);
    }
}

// ---------------------------------------------------------------------------
extern "C" void kernel_launch(void* const* d_in, const int* in_sizes, int n_in,
                              void* d_out, int out_size, void* d_ws, size_t ws_size,
                              hipStream_t stream) {
    const float* x    = (const float*)d_in[0];
    const float* Wqkv = (const float*)d_in[1];
    const float* bqkv = (const float*)d_in[2];
    const float* Wo   = (const float*)d_in[3];
    const float* bo   = (const float*)d_in[4];
    const float* ln1g = (const float*)d_in[5];
    const float* ln1b = (const float*)d_in[6];
    const float* W1   = (const float*)d_in[7];
    const float* b1   = (const float*)d_in[8];
    const float* W2   = (const float*)d_in[9];
    const float* b2   = (const float*)d_in[10];
    const float* ln2g = (const float*)d_in[11];
    const float* ln2b = (const float*)d_in[12];
    const float* lnfg = (const float*)d_in[13];
    const float* lnfb = (const float*)d_in[14];

    const int B = 4, S = 1024, D = 768, H = 12, F = 3072, L = 6;
    const int M = B * S;  // 4096

    char* p = (char*)d_ws;
    auto alloc = [&](size_t bytes) -> char* {
        char* r = p;
        p += (bytes + 255) & ~(size_t)255;
        return r;
    };
    float* h             = (float*)alloc((size_t)M * D * 4);
    float* tmp           = (float*)alloc((size_t)4 * M * D * 4);   // split-K partials
    unsigned short* hb   = (unsigned short*)alloc((size_t)M * D * 2);
    unsigned short* act  = (unsigned short*)alloc((size_t)M * F * 2); // qkv (18.9MB) / ffn1 (25.2MB) union
    unsigned short* Qb   = (unsigned short*)alloc((size_t)M * D * 2);
    unsigned short* Kb   = (unsigned short*)alloc((size_t)M * D * 2);
    unsigned short* Vtb  = (unsigned short*)alloc((size_t)M * D * 2);
    unsigned short* ctx  = (unsigned short*)alloc((size_t)M * D * 2);
    unsigned short* wqkvT = (unsigned short*)alloc((size_t)3 * D * D * 2);
    unsigned short* woT   = (unsigned short*)alloc((size_t)D * D * 2);
    unsigned short* w1T   = (unsigned short*)alloc((size_t)D * F * 2);
    unsigned short* w2T   = (unsigned short*)alloc((size_t)D * F * 2);
    unsigned short* qkvb = act;
    unsigned short* f1b  = act;

    posenc_k<<<(M * D) / 256, 256, 0, stream>>>(x, h, hb);

    for (int l = 0; l < L; ++l) {
        transpose_convert<<<dim3(3 * D / 32, D / 32), 256, 0, stream>>>(
            Wqkv + (size_t)l * D * 3 * D, wqkvT, D, 3 * D);
        transpose_convert<<<dim3(D / 32, D / 32), 256, 0, stream>>>(
            Wo + (size_t)l * D * D, woT, D, D);
        transpose_convert<<<dim3(F / 32, D / 32), 256, 0, stream>>>(
            W1 + (size_t)l * D * F, w1T, D, F);
        transpose_convert<<<dim3(D / 32, F / 32), 256, 0, stream>>>(
            W2 + (size_t)l * F * D, w2T, F, D);

        // qkv = hb @ WqkvT + bqkv (bf16)
        gemm_k<0, 1, 0, 1><<<dim3(3 * D / 128, M / 128, 1), 256, 0, stream>>>(
            hb, wqkvT, bqkv + (size_t)l * 3 * D, nullptr, qkvb, M, 3 * D, D, D);
        qksplit_k<<<786432 / 256, 256, 0, stream>>>(qkvb, Qb, Kb);
        vt_k<<<dim3(S / 64, B * H), 256, 0, stream>>>(qkvb, Vtb);
        flash_k<<<dim3(S / 64, B * H), 256, 0, stream>>>(Qb, Kb, Vtb, ctx);
        // attn out proj: split-K=2, partials to tmp (no bias)
        gemm_k<1, 0, 0, 0><<<dim3(D / 128, M / 128, 2), 256, 0, stream>>>(
            ctx, woT, nullptr, tmp, nullptr, M, D, D, D / 2);
        ln_k<2, 1><<<M, 256, 0, stream>>>(h, tmp, bo + (size_t)l * D,
                                          ln1g + (size_t)l * D, ln1b + (size_t)l * D,
                                          h, hb);
        // ffn1 (relu, bf16 out)
        gemm_k<0, 1, 1, 1><<<dim3(F / 128, M / 128, 1), 256, 0, stream>>>(
            hb, w1T, b1 + (size_t)l * F, nullptr, f1b, M, F, D, D);
        // ffn2: split-K=4, partials to tmp (no bias)
        gemm_k<1, 0, 0, 0><<<dim3(D / 128, M / 128, 4), 256, 0, stream>>>(
            f1b, w2T, nullptr, tmp, nullptr, M, D, F, F / 4);
        ln_k<4, 1><<<M, 256, 0, stream>>>(h, tmp, b2 + (size_t)l * D,
                                          ln2g + (size_t)l * D, ln2b + (size_t)l * D,
                                          h, hb);
    }
    ln_k<0, 0><<<M, 256, 0, stream>>>(h, nullptr, nullptr, lnfg, lnfb,
                                      (float*)d_out, nullptr);
}

// Round 4
// 1393.336 us; speedup vs baseline: 1.2717x; 1.0596x over previous
//
#include <hip/hip_runtime.h>
#include <math.h>

typedef float f32x4 __attribute__((ext_vector_type(4)));
typedef __bf16 bf16x8 __attribute__((ext_vector_type(8)));
typedef unsigned short u16x8 __attribute__((ext_vector_type(8)));

__device__ __forceinline__ unsigned short f2bf(float f) {
    union { float f; unsigned int u; } v; v.f = f;
    unsigned int r = v.u + 0x7FFFu + ((v.u >> 16) & 1u);
    return (unsigned short)(r >> 16);
}
__device__ __forceinline__ float bf2f(unsigned short u) {
    union { unsigned int u; float f; } v; v.u = ((unsigned int)u) << 16;
    return v.f;
}
__device__ __forceinline__ bf16x8 ld8(const unsigned short* p) {
    union { u16x8 u; bf16x8 b; } c;
    c.u = *(const u16x8*)p;
    return c.b;
}
__device__ __forceinline__ void gload_lds16(const unsigned short* g, unsigned short* l) {
    __builtin_amdgcn_global_load_lds(
        (const __attribute__((address_space(1))) unsigned int*)g,
        (__attribute__((address_space(3))) unsigned int*)l,
        16, 0, 0);
}
// [nrows][32]-short tile, XOR-swizzled chunk layout (0 bank conflicts, R2-verified)
__device__ __forceinline__ int swz_off(int row, int quad) {
    return row * 32 + ((quad ^ ((row >> 1) & 3)) << 3);
}

// ---------------------------------------------------------------------------
// Weight transpose + fp32->bf16 convert: W[K][N] -> Wt[N][K]
__global__ __launch_bounds__(256)
void transpose_convert(const float* __restrict__ W, unsigned short* __restrict__ Wt,
                       int K, int N) {
    __shared__ float tile[32][33];
    int n0 = blockIdx.x * 32, k0 = blockIdx.y * 32;
    int tx = threadIdx.x & 31, ty = threadIdx.x >> 5;
#pragma unroll
    for (int i = 0; i < 4; ++i) {
        int k = ty + i * 8;
        tile[k][tx] = W[(size_t)(k0 + k) * N + n0 + tx];
    }
    __syncthreads();
#pragma unroll
    for (int i = 0; i < 4; ++i) {
        int n = ty + i * 8;
        Wt[(size_t)(n0 + n) * K + k0 + tx] = f2bf(tile[tx][n]);
    }
}

// ---------------------------------------------------------------------------
__global__ __launch_bounds__(256)
void posenc_k(const float* __restrict__ x, float* __restrict__ h,
              unsigned short* __restrict__ hb) {
    int idx = blockIdx.x * 256 + threadIdx.x;
    const int TOT = 4 * 1024 * 768;
    if (idx >= TOT) return;
    int d = idx % 768;
    int s = (idx / 768) % 1024;
    int i2 = d >> 1;
    float dv = expf(-(float)(2 * i2) * (9.210340371976184f / 768.0f));
    float ang = (float)s * dv;
    float pe = (d & 1) ? cosf(ang) : sinf(ang);
    float v = x[idx] + pe;
    h[idx] = v;
    hb[idx] = f2bf(v);
}

// ---------------------------------------------------------------------------
// GEMM: C[M,N] = A[M,K](bf16) @ Bt[N,K](bf16)^T (+bias) (+relu), split-K via z.
template<int WF32, int WBF16, int RELU, int BIAS>
__global__ __launch_bounds__(256)
void gemm_k(const unsigned short* __restrict__ A, const unsigned short* __restrict__ Bt,
            const float* __restrict__ bias, float* __restrict__ Cf,
            unsigned short* __restrict__ Cb, int M, int N, int K, int Kc) {
    __shared__ unsigned short As[128 * 32];
    __shared__ unsigned short Bs[128 * 32];
    const int tid = threadIdx.x;
    const int lane = tid & 63, wave = tid >> 6;
    const int l15 = lane & 15, quad = lane >> 4;
    const int m0 = blockIdx.y * 128, n0 = blockIdx.x * 128;
    const int wr = (wave >> 1) * 64, wc = (wave & 1) * 64;
    const int kstart = blockIdx.z * Kc, kend = kstart + Kc;
    float* Cfp = Cf + (size_t)blockIdx.z * M * N;

    const int r0 = wave * 32 + (lane >> 2);
    const int kc0 = lane & 3;

    f32x4 acc[4][4];
#pragma unroll
    for (int i = 0; i < 4; ++i)
#pragma unroll
        for (int j = 0; j < 4; ++j) acc[i][j] = (f32x4){0.f, 0.f, 0.f, 0.f};

    for (int k0 = kstart; k0 < kend; k0 += 32) {
        __syncthreads();
#pragma unroll
        for (int j = 0; j < 2; ++j) {
            int r = r0 + j * 16;
            int kcl = kc0 ^ ((r >> 1) & 3);
            const unsigned short* ga = A + (size_t)(m0 + r) * K + k0 + kcl * 8;
            const unsigned short* gb = Bt + (size_t)(n0 + r) * K + k0 + kcl * 8;
            gload_lds16(ga, &As[(wave * 32 + j * 16) * 32]);
            gload_lds16(gb, &Bs[(wave * 32 + j * 16) * 32]);
        }
        __syncthreads();
        bf16x8 af[4], bfr[4];
#pragma unroll
        for (int mt = 0; mt < 4; ++mt)
            af[mt] = ld8(&As[swz_off(wr + mt * 16 + l15, quad)]);
#pragma unroll
        for (int nt = 0; nt < 4; ++nt)
            bfr[nt] = ld8(&Bs[swz_off(wc + nt * 16 + l15, quad)]);
#pragma unroll
        for (int mt = 0; mt < 4; ++mt)
#pragma unroll
            for (int nt = 0; nt < 4; ++nt)
                acc[mt][nt] = __builtin_amdgcn_mfma_f32_16x16x32_bf16(
                    af[mt], bfr[nt], acc[mt][nt], 0, 0, 0);
    }
#pragma unroll
    for (int mt = 0; mt < 4; ++mt)
#pragma unroll
        for (int nt = 0; nt < 4; ++nt)
#pragma unroll
            for (int r = 0; r < 4; ++r) {
                int row = m0 + wr + mt * 16 + quad * 4 + r;
                int col = n0 + wc + nt * 16 + l15;
                float v = acc[mt][nt][r];
                if (BIAS) v += bias[col];
                if (RELU) v = fmaxf(v, 0.f);
                if (WF32) Cfp[(size_t)row * N + col] = v;
                if (WBF16) Cb[(size_t)row * N + col] = f2bf(v);
            }
}

// ---------------------------------------------------------------------------
// Split qkv (bf16 [4096, 2304]) into Q (scaled 0.125) and K, [B,H,S,64] bf16.
__global__ __launch_bounds__(256)
void qksplit_k(const unsigned short* __restrict__ qkv, unsigned short* __restrict__ Q,
               unsigned short* __restrict__ Ko) {
    int o8 = blockIdx.x * 256 + threadIdx.x;
    const int NQ8 = 393216;
    int which = (o8 >= NQ8) ? 1 : 0;
    int oo = o8 - which * NQ8;
    int dg = (oo & 7) * 8;
    int s = (oo >> 3) & 1023;
    int bh = oo >> 13;
    int h = bh % 12, b = bh / 12;
    size_t row = (size_t)(b * 1024 + s);
    int col = which * 768 + h * 64 + dg;
    u16x8 val = *(const u16x8*)&qkv[row * 2304 + col];
    if (!which) {
#pragma unroll
        for (int j = 0; j < 8; ++j) val[j] = f2bf(bf2f(val[j]) * 0.125f);
        *(u16x8*)&Q[((size_t)bh * 1024 + s) * 64 + dg] = val;
    } else {
        *(u16x8*)&Ko[((size_t)bh * 1024 + s) * 64 + dg] = val;
    }
}

// V transpose: qkv v-part -> Vt[B,H,64(d),1024(s)] bf16. grid (S/64, B*H)
__global__ __launch_bounds__(256)
void vt_k(const unsigned short* __restrict__ qkv, unsigned short* __restrict__ Vt) {
    __shared__ unsigned short t[64][65];
    int bh = blockIdx.y, s0 = blockIdx.x * 64;
    int b = bh / 12, h = bh % 12;
    int tx = threadIdx.x & 63;
    int ty = threadIdx.x >> 6;
#pragma unroll
    for (int r = 0; r < 16; ++r) {
        int i = ty + r * 4;
        t[i][tx] = qkv[(size_t)(b * 1024 + s0 + i) * 2304 + 1536 + h * 64 + tx];
    }
    __syncthreads();
#pragma unroll
    for (int r = 0; r < 16; ++r) {
        int dd = ty + r * 4;
        Vt[((size_t)bh * 64 + dd) * 1024 + s0 + tx] = t[tx][dd];
    }
}

// ---------------------------------------------------------------------------
// Flash attention, fixed-max softmax (shift-invariant; scores << 88).
// Q,K [B,H,S,64] bf16 (Q pre-scaled by 1/8), Vt [B,H,64,S] bf16.
// Tiles stored as [128 rows][32 shorts] swizzled (k/s-halves = row blocks),
// staged via global_load_lds. Output ctx [B*S, 768] bf16.
#define PSTR 68
__global__ __launch_bounds__(256)
void flash_k(const unsigned short* __restrict__ Q, const unsigned short* __restrict__ K,
             const unsigned short* __restrict__ Vt, unsigned short* __restrict__ ctx) {
    const int S = 1024, HD = 64;
    int bh = blockIdx.y;
    int b = bh / 12, h = bh % 12;
    int q0 = blockIdx.x * 64;
    const unsigned short* Qp = Q + ((size_t)bh * S + q0) * HD;
    const unsigned short* Kp = K + (size_t)bh * S * HD;
    const unsigned short* Vp = Vt + (size_t)bh * HD * S;

    __shared__ unsigned short Qs[128 * 32];
    __shared__ unsigned short Ks[128 * 32];
    __shared__ unsigned short Vs[128 * 32];
    __shared__ unsigned short Ps[4 * 16 * PSTR];

    int tid = threadIdx.x;
    int lane = tid & 63, wave = tid >> 6;
    int l15 = lane & 15, quad = lane >> 4;

    // staging geometry: instr j covers LDS rows [wave*32+j*16, +16)
    const int rl0 = lane >> 2;          // row within 16-row block
    const int c0 = lane & 3;            // phys chunk

    // Stage Q once: LDS row R = khalf*64 + qrow
#pragma unroll
    for (int j = 0; j < 2; ++j) {
        int R = wave * 32 + j * 16 + rl0;
        int khalf = R >> 6, grow = R & 63;
        int lch = c0 ^ ((R >> 1) & 3);
        gload_lds16(Qp + grow * HD + khalf * 32 + lch * 8,
                    &Qs[(wave * 32 + j * 16) * 32]);
    }

    f32x4 o[4];
#pragma unroll
    for (int i = 0; i < 4; ++i) o[i] = (f32x4){0.f, 0.f, 0.f, 0.f};
    float lsum[4] = {0.f, 0.f, 0.f, 0.f};

    unsigned short* Pw = &Ps[wave * 16 * PSTR];

    for (int kt = 0; kt < 16; ++kt) {
        __syncthreads();
#pragma unroll
        for (int j = 0; j < 2; ++j) {
            int R = wave * 32 + j * 16 + rl0;
            int khalf = R >> 6, grow = R & 63;
            int lch = c0 ^ ((R >> 1) & 3);
            // K tile rows = k-positions
            gload_lds16(Kp + (kt * 64 + grow) * HD + khalf * 32 + lch * 8,
                        &Ks[(wave * 32 + j * 16) * 32]);
            // V tile rows = d (Vt layout [d][s])
            gload_lds16(Vp + (size_t)grow * S + kt * 64 + khalf * 32 + lch * 8,
                        &Vs[(wave * 32 + j * 16) * 32]);
        }
        __syncthreads();

        bf16x8 qa0 = ld8(&Qs[swz_off(wave * 16 + l15, quad)]);
        bf16x8 qa1 = ld8(&Qs[swz_off(64 + wave * 16 + l15, quad)]);
        f32x4 sc[4];
#pragma unroll
        for (int cb = 0; cb < 4; ++cb) {
            bf16x8 kb0 = ld8(&Ks[swz_off(cb * 16 + l15, quad)]);
            bf16x8 kb1 = ld8(&Ks[swz_off(64 + cb * 16 + l15, quad)]);
            f32x4 z = (f32x4){0.f, 0.f, 0.f, 0.f};
            z = __builtin_amdgcn_mfma_f32_16x16x32_bf16(qa0, kb0, z, 0, 0, 0);
            z = __builtin_amdgcn_mfma_f32_16x16x32_bf16(qa1, kb1, z, 0, 0, 0);
            sc[cb] = z;
        }
        // exp (no max shift needed; |score| << 88) + per-lane partial row sums
#pragma unroll
        for (int cb = 0; cb < 4; ++cb)
#pragma unroll
            for (int r = 0; r < 4; ++r) {
                float pv = __expf(sc[cb][r]);
                sc[cb][r] = pv;
                lsum[r] += pv;
            }
        // P (C-layout) -> LDS -> A-operand layout (per-wave region, no barrier)
#pragma unroll
        for (int cb = 0; cb < 4; ++cb)
#pragma unroll
            for (int r = 0; r < 4; ++r)
                Pw[(quad * 4 + r) * PSTR + cb * 16 + l15] = f2bf(sc[cb][r]);
        bf16x8 pa0 = ld8(&Pw[l15 * PSTR + quad * 8]);
        bf16x8 pa1 = ld8(&Pw[l15 * PSTR + 32 + quad * 8]);
#pragma unroll
        for (int cb = 0; cb < 4; ++cb) {
            bf16x8 vb0 = ld8(&Vs[swz_off(cb * 16 + l15, quad)]);
            bf16x8 vb1 = ld8(&Vs[swz_off(64 + cb * 16 + l15, quad)]);
            o[cb] = __builtin_amdgcn_mfma_f32_16x16x32_bf16(pa0, vb0, o[cb], 0, 0, 0);
            o[cb] = __builtin_amdgcn_mfma_f32_16x16x32_bf16(pa1, vb1, o[cb], 0, 0, 0);
        }
    }
    // final row-sum reduce across the 16 lanes holding each row's columns
#pragma unroll
    for (int r = 0; r < 4; ++r) {
#pragma unroll
        for (int off = 1; off < 16; off <<= 1) lsum[r] += __shfl_xor(lsum[r], off);
    }
#pragma unroll
    for (int cb = 0; cb < 4; ++cb)
#pragma unroll
        for (int r = 0; r < 4; ++r) {
            int row = q0 + wave * 16 + quad * 4 + r;
            float val = o[cb][r] / lsum[r];
            ctx[((size_t)(b * 1024 + row)) * 768 + h * 64 + cb * 16 + l15] = f2bf(val);
        }
}

// ---------------------------------------------------------------------------
// LayerNorm over D=768. NPART>0: residual = X + sum(partials) + proj-bias.
template<int NPART, int WBF16>
__global__ __launch_bounds__(256)
void ln_k(const float* __restrict__ X, const float* __restrict__ P,
          const float* __restrict__ pb,
          const float* __restrict__ g, const float* __restrict__ bta,
          float* __restrict__ Yf, unsigned short* __restrict__ Yb) {
    const int D = 768;
    const size_t MD = (size_t)4096 * 768;
    int row = blockIdx.x;
    int tid = threadIdx.x;
    const float* x = X + (size_t)row * D;
    float v[3];
    float s = 0.f, s2 = 0.f;
#pragma unroll
    for (int i = 0; i < 3; ++i) {
        int c = i * 256 + tid;
        float t = x[c];
        if (NPART > 0) {
            float r = pb[c];
#pragma unroll
            for (int pi = 0; pi < NPART; ++pi)
                r += P[MD * pi + (size_t)row * D + c];
            t += r;
        }
        v[i] = t;
        s += t;
        s2 += t * t;
    }
#pragma unroll
    for (int off = 1; off < 64; off <<= 1) {
        s += __shfl_xor(s, off);
        s2 += __shfl_xor(s2, off);
    }
    __shared__ float rs[4], rs2[4];
    int wave = tid >> 6, lane = tid & 63;
    if (lane == 0) { rs[wave] = s; rs2[wave] = s2; }
    __syncthreads();
    s = rs[0] + rs[1] + rs[2] + rs[3];
    s2 = rs2[0] + rs2[1] + rs2[2] + rs2[3];
    float mu = s * (1.f / 768.f);
    float var = s2 * (1.f / 768.f) - mu * mu;
    float rstd = rsqrtf(var + 1e-5f);
#pragma unroll
    for (int i = 0; i < 3; ++i) {
        int c = i * 256 + tid;
        float y = (v[i] - mu) * rstd * g[c] + bta[c];
        Yf[(size_t)row * D + c] = y;
        if (WBF16) Yb[(size_t)row * D + c] = f2bf(y);
    }
}

// ---------------------------------------------------------------------------
extern "C" void kernel_launch(void* const* d_in, const int* in_sizes, int n_in,
                              void* d_out, int out_size, void* d_ws, size_t ws_size,
                              hipStream_t stream) {
    const float* x    = (const float*)d_in[0];
    const float* Wqkv = (const float*)d_in[1];
    const float* bqkv = (const float*)d_in[2];
    const float* Wo   = (const float*)d_in[3];
    const float* bo   = (const float*)d_in[4];
    const float* ln1g = (const float*)d_in[5];
    const float* ln1b = (const float*)d_in[6];
    const float* W1   = (const float*)d_in[7];
    const float* b1   = (const float*)d_in[8];
    const float* W2   = (const float*)d_in[9];
    const float* b2   = (const float*)d_in[10];
    const float* ln2g = (const float*)d_in[11];
    const float* ln2b = (const float*)d_in[12];
    const float* lnfg = (const float*)d_in[13];
    const float* lnfb = (const float*)d_in[14];

    const int B = 4, S = 1024, D = 768, H = 12, F = 3072, L = 6;
    const int M = B * S;  // 4096

    char* p = (char*)d_ws;
    auto alloc = [&](size_t bytes) -> char* {
        char* r = p;
        p += (bytes + 255) & ~(size_t)255;
        return r;
    };
    float* h             = (float*)alloc((size_t)M * D * 4);
    float* tmp           = (float*)alloc((size_t)4 * M * D * 4);   // split-K partials
    unsigned short* hb   = (unsigned short*)alloc((size_t)M * D * 2);
    unsigned short* act  = (unsigned short*)alloc((size_t)M * F * 2); // qkv / ffn1 union
    unsigned short* Qb   = (unsigned short*)alloc((size_t)M * D * 2);
    unsigned short* Kb   = (unsigned short*)alloc((size_t)M * D * 2);
    unsigned short* Vtb  = (unsigned short*)alloc((size_t)M * D * 2);
    unsigned short* ctx  = (unsigned short*)alloc((size_t)M * D * 2);
    unsigned short* wqkvT = (unsigned short*)alloc((size_t)3 * D * D * 2);
    unsigned short* woT   = (unsigned short*)alloc((size_t)D * D * 2);
    unsigned short* w1T   = (unsigned short*)alloc((size_t)D * F * 2);
    unsigned short* w2T   = (unsigned short*)alloc((size_t)D * F * 2);
    unsigned short* qkvb = act;
    unsigned short* f1b  = act;

    posenc_k<<<(M * D) / 256, 256, 0, stream>>>(x, h, hb);

    for (int l = 0; l < L; ++l) {
        transpose_convert<<<dim3(3 * D / 32, D / 32), 256, 0, stream>>>(
            Wqkv + (size_t)l * D * 3 * D, wqkvT, D, 3 * D);
        transpose_convert<<<dim3(D / 32, D / 32), 256, 0, stream>>>(
            Wo + (size_t)l * D * D, woT, D, D);
        transpose_convert<<<dim3(F / 32, D / 32), 256, 0, stream>>>(
            W1 + (size_t)l * D * F, w1T, D, F);
        transpose_convert<<<dim3(D / 32, F / 32), 256, 0, stream>>>(
            W2 + (size_t)l * F * D, w2T, F, D);

        gemm_k<0, 1, 0, 1><<<dim3(3 * D / 128, M / 128, 1), 256, 0, stream>>>(
            hb, wqkvT, bqkv + (size_t)l * 3 * D, nullptr, qkvb, M, 3 * D, D, D);
        qksplit_k<<<786432 / 256, 256, 0, stream>>>(qkvb, Qb, Kb);
        vt_k<<<dim3(S / 64, B * H), 256, 0, stream>>>(qkvb, Vtb);
        flash_k<<<dim3(S / 64, B * H), 256, 0, stream>>>(Qb, Kb, Vtb, ctx);
        gemm_k<1, 0, 0, 0><<<dim3(D / 128, M / 128, 2), 256, 0, stream>>>(
            ctx, woT, nullptr, tmp, nullptr, M, D, D, D / 2);
        ln_k<2, 1><<<M, 256, 0, stream>>>(h, tmp, bo + (size_t)l * D,
                                          ln1g + (size_t)l * D, ln1b + (size_t)l * D,
                                          h, hb);
        gemm_k<0, 1, 1, 1><<<dim3(F / 128, M / 128, 1), 256, 0, stream>>>(
            hb, w1T, b1 + (size_t)l * F, nullptr, f1b, M, F, D, D);
        gemm_k<1, 0, 0, 0><<<dim3(D / 128, M / 128, 4), 256, 0, stream>>>(
            f1b, w2T, nullptr, tmp, nullptr, M, D, F, F / 4);
        ln_k<4, 1><<<M, 256, 0, stream>>>(h, tmp, b2 + (size_t)l * D,
                                          ln2g + (size_t)l * D, ln2b + (size_t)l * D,
                                          h, hb);
    }
    ln_k<0, 0><<<M, 256, 0, stream>>>(h, nullptr, nullptr, lnfg, lnfb,
                                      (float*)d_out, nullptr);
}

// Round 5
// 1319.251 us; speedup vs baseline: 1.3431x; 1.0562x over previous
//
#include <hip/hip_runtime.h>
#include <math.h>

typedef float f32x4 __attribute__((ext_vector_type(4)));
typedef __bf16 bf16x8 __attribute__((ext_vector_type(8)));
typedef unsigned short u16x8 __attribute__((ext_vector_type(8)));

__device__ __forceinline__ unsigned short f2bf(float f) {
    union { float f; unsigned int u; } v; v.f = f;
    unsigned int r = v.u + 0x7FFFu + ((v.u >> 16) & 1u);
    return (unsigned short)(r >> 16);
}
__device__ __forceinline__ float bf2f(unsigned short u) {
    union { unsigned int u; float f; } v; v.u = ((unsigned int)u) << 16;
    return v.f;
}
__device__ __forceinline__ bf16x8 ld8(const unsigned short* p) {
    union { u16x8 u; bf16x8 b; } c;
    c.u = *(const u16x8*)p;
    return c.b;
}
__device__ __forceinline__ void gload_lds16(const unsigned short* g, unsigned short* l) {
    __builtin_amdgcn_global_load_lds(
        (const __attribute__((address_space(1))) unsigned int*)g,
        (__attribute__((address_space(3))) unsigned int*)l,
        16, 0, 0);
}
// [nrows][32]-short tile, XOR-swizzled chunk layout (0 bank conflicts, R2-verified)
__device__ __forceinline__ int swz_off(int row, int quad) {
    return row * 32 + ((quad ^ ((row >> 1) & 3)) << 3);
}

// ---------------------------------------------------------------------------
// Weight transpose + fp32->bf16 convert: W[K][N] -> Wt[N][K]
__global__ __launch_bounds__(256)
void transpose_convert(const float* __restrict__ W, unsigned short* __restrict__ Wt,
                       int K, int N) {
    __shared__ float tile[32][33];
    int n0 = blockIdx.x * 32, k0 = blockIdx.y * 32;
    int tx = threadIdx.x & 31, ty = threadIdx.x >> 5;
#pragma unroll
    for (int i = 0; i < 4; ++i) {
        int k = ty + i * 8;
        tile[k][tx] = W[(size_t)(k0 + k) * N + n0 + tx];
    }
    __syncthreads();
#pragma unroll
    for (int i = 0; i < 4; ++i) {
        int n = ty + i * 8;
        Wt[(size_t)(n0 + n) * K + k0 + tx] = f2bf(tile[tx][n]);
    }
}

// ---------------------------------------------------------------------------
__global__ __launch_bounds__(256)
void posenc_k(const float* __restrict__ x, float* __restrict__ h,
              unsigned short* __restrict__ hb) {
    int idx = blockIdx.x * 256 + threadIdx.x;
    const int TOT = 4 * 1024 * 768;
    if (idx >= TOT) return;
    int d = idx % 768;
    int s = (idx / 768) % 1024;
    int i2 = d >> 1;
    float dv = expf(-(float)(2 * i2) * (9.210340371976184f / 768.0f));
    float ang = (float)s * dv;
    float pe = (d & 1) ? cosf(ang) : sinf(ang);
    float v = x[idx] + pe;
    h[idx] = v;
    hb[idx] = f2bf(v);
}

// ---------------------------------------------------------------------------
// GEMM: C[M,N] = A[M,K](bf16) @ Bt[N,K](bf16)^T (+bias) (+relu), split-K via z.
// Output always bf16 (split-K partials are bf16 too; combined in ln_k).
// Single-barrier double-buffered staging: prefetch t+1 overlaps compute of t.
template<int RELU, int BIAS>
__global__ __launch_bounds__(256)
void gemm_k(const unsigned short* __restrict__ A, const unsigned short* __restrict__ Bt,
            const float* __restrict__ bias, unsigned short* __restrict__ Cb,
            int M, int N, int K, int Kc) {
    __shared__ unsigned short As[2][128 * 32];
    __shared__ unsigned short Bs[2][128 * 32];
    const int tid = threadIdx.x;
    const int lane = tid & 63, wave = tid >> 6;
    const int l15 = lane & 15, quad = lane >> 4;
    const int m0 = blockIdx.y * 128, n0 = blockIdx.x * 128;
    const int wr = (wave >> 1) * 64, wc = (wave & 1) * 64;
    const int kstart = blockIdx.z * Kc;
    unsigned short* Cbp = Cb + (size_t)blockIdx.z * M * N;

    const int r0 = wave * 32 + (lane >> 2);
    const int kc0 = lane & 3;

    auto stage = [&](int k0, int bi) {
#pragma unroll
        for (int j = 0; j < 2; ++j) {
            int r = r0 + j * 16;
            int kcl = kc0 ^ ((r >> 1) & 3);
            gload_lds16(A + (size_t)(m0 + r) * K + k0 + kcl * 8,
                        &As[bi][(wave * 32 + j * 16) * 32]);
            gload_lds16(Bt + (size_t)(n0 + r) * K + k0 + kcl * 8,
                        &Bs[bi][(wave * 32 + j * 16) * 32]);
        }
    };

    f32x4 acc[4][4];
#pragma unroll
    for (int i = 0; i < 4; ++i)
#pragma unroll
        for (int j = 0; j < 4; ++j) acc[i][j] = (f32x4){0.f, 0.f, 0.f, 0.f};

    stage(kstart, 0);
    const int nk = Kc / 32;
    for (int t = 0; t < nk; ++t) {
        __syncthreads();                       // drains prev prefetch (vmcnt) + read-WAR
        if (t + 1 < nk) stage(kstart + (t + 1) * 32, (t + 1) & 1);
        const unsigned short* Asb = As[t & 1];
        const unsigned short* Bsb = Bs[t & 1];
        bf16x8 af[4], bfr[4];
#pragma unroll
        for (int mt = 0; mt < 4; ++mt)
            af[mt] = ld8(&Asb[swz_off(wr + mt * 16 + l15, quad)]);
#pragma unroll
        for (int nt = 0; nt < 4; ++nt)
            bfr[nt] = ld8(&Bsb[swz_off(wc + nt * 16 + l15, quad)]);
#pragma unroll
        for (int mt = 0; mt < 4; ++mt)
#pragma unroll
            for (int nt = 0; nt < 4; ++nt)
                acc[mt][nt] = __builtin_amdgcn_mfma_f32_16x16x32_bf16(
                    af[mt], bfr[nt], acc[mt][nt], 0, 0, 0);
    }
#pragma unroll
    for (int mt = 0; mt < 4; ++mt)
#pragma unroll
        for (int nt = 0; nt < 4; ++nt)
#pragma unroll
            for (int r = 0; r < 4; ++r) {
                int row = m0 + wr + mt * 16 + quad * 4 + r;
                int col = n0 + wc + nt * 16 + l15;
                float v = acc[mt][nt][r];
                if (BIAS) v += bias[col];
                if (RELU) v = fmaxf(v, 0.f);
                Cbp[(size_t)row * N + col] = f2bf(v);
            }
}

// ---------------------------------------------------------------------------
// Split qkv (bf16 [4096, 2304]) into Q (scaled 0.125) and K, [B,H,S,64] bf16.
__global__ __launch_bounds__(256)
void qksplit_k(const unsigned short* __restrict__ qkv, unsigned short* __restrict__ Q,
               unsigned short* __restrict__ Ko) {
    int o8 = blockIdx.x * 256 + threadIdx.x;
    const int NQ8 = 393216;
    int which = (o8 >= NQ8) ? 1 : 0;
    int oo = o8 - which * NQ8;
    int dg = (oo & 7) * 8;
    int s = (oo >> 3) & 1023;
    int bh = oo >> 13;
    int h = bh % 12, b = bh / 12;
    size_t row = (size_t)(b * 1024 + s);
    int col = which * 768 + h * 64 + dg;
    u16x8 val = *(const u16x8*)&qkv[row * 2304 + col];
    if (!which) {
#pragma unroll
        for (int j = 0; j < 8; ++j) val[j] = f2bf(bf2f(val[j]) * 0.125f);
        *(u16x8*)&Q[((size_t)bh * 1024 + s) * 64 + dg] = val;
    } else {
        *(u16x8*)&Ko[((size_t)bh * 1024 + s) * 64 + dg] = val;
    }
}

// V transpose: qkv v-part -> Vt[B,H,64(d),1024(s)] bf16. grid (S/64, B*H)
__global__ __launch_bounds__(256)
void vt_k(const unsigned short* __restrict__ qkv, unsigned short* __restrict__ Vt) {
    __shared__ unsigned short t[64][65];
    int bh = blockIdx.y, s0 = blockIdx.x * 64;
    int b = bh / 12, h = bh % 12;
    int tx = threadIdx.x & 63;
    int ty = threadIdx.x >> 6;
#pragma unroll
    for (int r = 0; r < 16; ++r) {
        int i = ty + r * 4;
        t[i][tx] = qkv[(size_t)(b * 1024 + s0 + i) * 2304 + 1536 + h * 64 + tx];
    }
    __syncthreads();
#pragma unroll
    for (int r = 0; r < 16; ++r) {
        int dd = ty + r * 4;
        Vt[((size_t)bh * 64 + dd) * 1024 + s0 + tx] = t[tx][dd];
    }
}

// ---------------------------------------------------------------------------
// Flash attention, fixed-max softmax (shift-invariant; scores << 88).
// Q,K [B,H,S,64] bf16 (Q pre-scaled by 1/8), Vt [B,H,64,S] bf16.
// Double-buffered K/V staging via global_load_lds: one barrier per k-tile,
// prefetch of kt+1 in flight across the compute of kt.
#define PSTR 68
__global__ __launch_bounds__(256)
void flash_k(const unsigned short* __restrict__ Q, const unsigned short* __restrict__ K,
             const unsigned short* __restrict__ Vt, unsigned short* __restrict__ ctx) {
    const int S = 1024, HD = 64;
    int bh = blockIdx.y;
    int b = bh / 12, h = bh % 12;
    int q0 = blockIdx.x * 64;
    const unsigned short* Qp = Q + ((size_t)bh * S + q0) * HD;
    const unsigned short* Kp = K + (size_t)bh * S * HD;
    const unsigned short* Vp = Vt + (size_t)bh * HD * S;

    __shared__ unsigned short Qs[128 * 32];
    __shared__ unsigned short Ks[2][128 * 32];
    __shared__ unsigned short Vs[2][128 * 32];
    __shared__ unsigned short Ps[4 * 16 * PSTR];

    int tid = threadIdx.x;
    int lane = tid & 63, wave = tid >> 6;
    int l15 = lane & 15, quad = lane >> 4;

    const int rl0 = lane >> 2;          // row within 16-row staging block
    const int c0 = lane & 3;            // phys chunk

    auto stageKV = [&](int kt, int bi) {
#pragma unroll
        for (int j = 0; j < 2; ++j) {
            int R = wave * 32 + j * 16 + rl0;
            int khalf = R >> 6, grow = R & 63;
            int lch = c0 ^ ((R >> 1) & 3);
            gload_lds16(Kp + (kt * 64 + grow) * HD + khalf * 32 + lch * 8,
                        &Ks[bi][(wave * 32 + j * 16) * 32]);
            gload_lds16(Vp + (size_t)grow * S + kt * 64 + khalf * 32 + lch * 8,
                        &Vs[bi][(wave * 32 + j * 16) * 32]);
        }
    };

    // Stage Q once: LDS row R = khalf*64 + qrow
#pragma unroll
    for (int j = 0; j < 2; ++j) {
        int R = wave * 32 + j * 16 + rl0;
        int khalf = R >> 6, grow = R & 63;
        int lch = c0 ^ ((R >> 1) & 3);
        gload_lds16(Qp + grow * HD + khalf * 32 + lch * 8,
                    &Qs[(wave * 32 + j * 16) * 32]);
    }
    stageKV(0, 0);

    f32x4 o[4];
#pragma unroll
    for (int i = 0; i < 4; ++i) o[i] = (f32x4){0.f, 0.f, 0.f, 0.f};
    float lsum[4] = {0.f, 0.f, 0.f, 0.f};

    unsigned short* Pw = &Ps[wave * 16 * PSTR];

    for (int kt = 0; kt < 16; ++kt) {
        __syncthreads();                     // drains current tile's staging
        if (kt < 15) stageKV(kt + 1, (kt + 1) & 1);
        const unsigned short* Ksb = Ks[kt & 1];
        const unsigned short* Vsb = Vs[kt & 1];

        bf16x8 qa0 = ld8(&Qs[swz_off(wave * 16 + l15, quad)]);
        bf16x8 qa1 = ld8(&Qs[swz_off(64 + wave * 16 + l15, quad)]);
        f32x4 sc[4];
#pragma unroll
        for (int cb = 0; cb < 4; ++cb) {
            bf16x8 kb0 = ld8(&Ksb[swz_off(cb * 16 + l15, quad)]);
            bf16x8 kb1 = ld8(&Ksb[swz_off(64 + cb * 16 + l15, quad)]);
            f32x4 z = (f32x4){0.f, 0.f, 0.f, 0.f};
            z = __builtin_amdgcn_mfma_f32_16x16x32_bf16(qa0, kb0, z, 0, 0, 0);
            z = __builtin_amdgcn_mfma_f32_16x16x32_bf16(qa1, kb1, z, 0, 0, 0);
            sc[cb] = z;
        }
        // exp (no max shift; |score| << 88) + per-lane partial row sums
#pragma unroll
        for (int cb = 0; cb < 4; ++cb)
#pragma unroll
            for (int r = 0; r < 4; ++r) {
                float pv = __expf(sc[cb][r]);
                sc[cb][r] = pv;
                lsum[r] += pv;
            }
        // P (C-layout) -> LDS -> A-operand layout (per-wave region, no barrier)
#pragma unroll
        for (int cb = 0; cb < 4; ++cb)
#pragma unroll
            for (int r = 0; r < 4; ++r)
                Pw[(quad * 4 + r) * PSTR + cb * 16 + l15] = f2bf(sc[cb][r]);
        bf16x8 pa0 = ld8(&Pw[l15 * PSTR + quad * 8]);
        bf16x8 pa1 = ld8(&Pw[l15 * PSTR + 32 + quad * 8]);
#pragma unroll
        for (int cb = 0; cb < 4; ++cb) {
            bf16x8 vb0 = ld8(&Vsb[swz_off(cb * 16 + l15, quad)]);
            bf16x8 vb1 = ld8(&Vsb[swz_off(64 + cb * 16 + l15, quad)]);
            o[cb] = __builtin_amdgcn_mfma_f32_16x16x32_bf16(pa0, vb0, o[cb], 0, 0, 0);
            o[cb] = __builtin_amdgcn_mfma_f32_16x16x32_bf16(pa1, vb1, o[cb], 0, 0, 0);
        }
    }
#pragma unroll
    for (int r = 0; r < 4; ++r) {
#pragma unroll
        for (int off = 1; off < 16; off <<= 1) lsum[r] += __shfl_xor(lsum[r], off);
    }
#pragma unroll
    for (int cb = 0; cb < 4; ++cb)
#pragma unroll
        for (int r = 0; r < 4; ++r) {
            int row = q0 + wave * 16 + quad * 4 + r;
            float val = o[cb][r] / lsum[r];
            ctx[((size_t)(b * 1024 + row)) * 768 + h * 64 + cb * 16 + l15] = f2bf(val);
        }
}

// ---------------------------------------------------------------------------
// LayerNorm over D=768. NPART>0: residual = X + sum(bf16 partials) + proj-bias.
template<int NPART, int WBF16>
__global__ __launch_bounds__(256)
void ln_k(const float* __restrict__ X, const unsigned short* __restrict__ P,
          const float* __restrict__ pb,
          const float* __restrict__ g, const float* __restrict__ bta,
          float* __restrict__ Yf, unsigned short* __restrict__ Yb) {
    const int D = 768;
    const size_t MD = (size_t)4096 * 768;
    int row = blockIdx.x;
    int tid = threadIdx.x;
    const float* x = X + (size_t)row * D;
    float v[3];
    float s = 0.f, s2 = 0.f;
#pragma unroll
    for (int i = 0; i < 3; ++i) {
        int c = i * 256 + tid;
        float t = x[c];
        if (NPART > 0) {
            float r = pb[c];
#pragma unroll
            for (int pi = 0; pi < NPART; ++pi)
                r += bf2f(P[MD * pi + (size_t)row * D + c]);
            t += r;
        }
        v[i] = t;
        s += t;
        s2 += t * t;
    }
#pragma unroll
    for (int off = 1; off < 64; off <<= 1) {
        s += __shfl_xor(s, off);
        s2 += __shfl_xor(s2, off);
    }
    __shared__ float rs[4], rs2[4];
    int wave = tid >> 6, lane = tid & 63;
    if (lane == 0) { rs[wave] = s; rs2[wave] = s2; }
    __syncthreads();
    s = rs[0] + rs[1] + rs[2] + rs[3];
    s2 = rs2[0] + rs2[1] + rs2[2] + rs2[3];
    float mu = s * (1.f / 768.f);
    float var = s2 * (1.f / 768.f) - mu * mu;
    float rstd = rsqrtf(var + 1e-5f);
#pragma unroll
    for (int i = 0; i < 3; ++i) {
        int c = i * 256 + tid;
        float y = (v[i] - mu) * rstd * g[c] + bta[c];
        Yf[(size_t)row * D + c] = y;
        if (WBF16) Yb[(size_t)row * D + c] = f2bf(y);
    }
}

// ---------------------------------------------------------------------------
extern "C" void kernel_launch(void* const* d_in, const int* in_sizes, int n_in,
                              void* d_out, int out_size, void* d_ws, size_t ws_size,
                              hipStream_t stream) {
    const float* x    = (const float*)d_in[0];
    const float* Wqkv = (const float*)d_in[1];
    const float* bqkv = (const float*)d_in[2];
    const float* Wo   = (const float*)d_in[3];
    const float* bo   = (const float*)d_in[4];
    const float* ln1g = (const float*)d_in[5];
    const float* ln1b = (const float*)d_in[6];
    const float* W1   = (const float*)d_in[7];
    const float* b1   = (const float*)d_in[8];
    const float* W2   = (const float*)d_in[9];
    const float* b2   = (const float*)d_in[10];
    const float* ln2g = (const float*)d_in[11];
    const float* ln2b = (const float*)d_in[12];
    const float* lnfg = (const float*)d_in[13];
    const float* lnfb = (const float*)d_in[14];

    const int B = 4, S = 1024, D = 768, H = 12, F = 3072, L = 6;
    const int M = B * S;  // 4096

    char* p = (char*)d_ws;
    auto alloc = [&](size_t bytes) -> char* {
        char* r = p;
        p += (bytes + 255) & ~(size_t)255;
        return r;
    };
    float* h             = (float*)alloc((size_t)M * D * 4);
    unsigned short* tmp  = (unsigned short*)alloc((size_t)4 * M * D * 2); // bf16 split-K partials
    unsigned short* hb   = (unsigned short*)alloc((size_t)M * D * 2);
    unsigned short* act  = (unsigned short*)alloc((size_t)M * F * 2); // qkv / ffn1 union
    unsigned short* Qb   = (unsigned short*)alloc((size_t)M * D * 2);
    unsigned short* Kb   = (unsigned short*)alloc((size_t)M * D * 2);
    unsigned short* Vtb  = (unsigned short*)alloc((size_t)M * D * 2);
    unsigned short* ctx  = (unsigned short*)alloc((size_t)M * D * 2);
    unsigned short* wqkvT = (unsigned short*)alloc((size_t)3 * D * D * 2);
    unsigned short* woT   = (unsigned short*)alloc((size_t)D * D * 2);
    unsigned short* w1T   = (unsigned short*)alloc((size_t)D * F * 2);
    unsigned short* w2T   = (unsigned short*)alloc((size_t)D * F * 2);
    unsigned short* qkvb = act;
    unsigned short* f1b  = act;

    posenc_k<<<(M * D) / 256, 256, 0, stream>>>(x, h, hb);

    for (int l = 0; l < L; ++l) {
        transpose_convert<<<dim3(3 * D / 32, D / 32), 256, 0, stream>>>(
            Wqkv + (size_t)l * D * 3 * D, wqkvT, D, 3 * D);
        transpose_convert<<<dim3(D / 32, D / 32), 256, 0, stream>>>(
            Wo + (size_t)l * D * D, woT, D, D);
        transpose_convert<<<dim3(F / 32, D / 32), 256, 0, stream>>>(
            W1 + (size_t)l * D * F, w1T, D, F);
        transpose_convert<<<dim3(D / 32, F / 32), 256, 0, stream>>>(
            W2 + (size_t)l * F * D, w2T, F, D);

        // qkv = hb @ WqkvT + bqkv (bf16)
        gemm_k<0, 1><<<dim3(3 * D / 128, M / 128, 1), 256, 0, stream>>>(
            hb, wqkvT, bqkv + (size_t)l * 3 * D, qkvb, M, 3 * D, D, D);
        qksplit_k<<<786432 / 256, 256, 0, stream>>>(qkvb, Qb, Kb);
        vt_k<<<dim3(S / 64, B * H), 256, 0, stream>>>(qkvb, Vtb);
        flash_k<<<dim3(S / 64, B * H), 256, 0, stream>>>(Qb, Kb, Vtb, ctx);
        // attn out proj: split-K=4, bf16 partials (no bias)
        gemm_k<0, 0><<<dim3(D / 128, M / 128, 4), 256, 0, stream>>>(
            ctx, woT, nullptr, tmp, M, D, D, D / 4);
        ln_k<4, 1><<<M, 256, 0, stream>>>(h, tmp, bo + (size_t)l * D,
                                          ln1g + (size_t)l * D, ln1b + (size_t)l * D,
                                          h, hb);
        // ffn1 (relu, bf16 out)
        gemm_k<1, 1><<<dim3(F / 128, M / 128, 1), 256, 0, stream>>>(
            hb, w1T, b1 + (size_t)l * F, f1b, M, F, D, D);
        // ffn2: split-K=4, bf16 partials (no bias)
        gemm_k<0, 0><<<dim3(D / 128, M / 128, 4), 256, 0, stream>>>(
            f1b, w2T, nullptr, tmp, M, D, F, F / 4);
        ln_k<4, 1><<<M, 256, 0, stream>>>(h, tmp, b2 + (size_t)l * D,
                                          ln2g + (size_t)l * D, ln2b + (size_t)l * D,
                                          h, hb);
    }
    ln_k<0, 0><<<M, 256, 0, stream>>>(h, nullptr, nullptr, lnfg, lnfb,
                                      (float*)d_out, nullptr);
}

// Round 6
// 1222.077 us; speedup vs baseline: 1.4499x; 1.0795x over previous
//
#include <hip/hip_runtime.h>
#include <math.h>

typedef float f32x4 __attribute__((ext_vector_type(4)));
typedef __bf16 bf16x8 __attribute__((ext_vector_type(8)));
typedef unsigned short u16x8 __attribute__((ext_vector_type(8)));

__device__ __forceinline__ unsigned short f2bf(float f) {
    union { float f; unsigned int u; } v; v.f = f;
    unsigned int r = v.u + 0x7FFFu + ((v.u >> 16) & 1u);
    return (unsigned short)(r >> 16);
}
__device__ __forceinline__ unsigned short f2bft(float f) {  // truncate (1 VALU op)
    union { float f; unsigned int u; } v; v.f = f;
    return (unsigned short)(v.u >> 16);
}
__device__ __forceinline__ float bf2f(unsigned short u) {
    union { unsigned int u; float f; } v; v.u = ((unsigned int)u) << 16;
    return v.f;
}
__device__ __forceinline__ bf16x8 ld8(const unsigned short* p) {
    union { u16x8 u; bf16x8 b; } c;
    c.u = *(const u16x8*)p;
    return c.b;
}
__device__ __forceinline__ void gload_lds16(const unsigned short* g, unsigned short* l) {
    __builtin_amdgcn_global_load_lds(
        (const __attribute__((address_space(1))) unsigned int*)g,
        (__attribute__((address_space(3))) unsigned int*)l,
        16, 0, 0);
}
// [nrows][32]-short tile, XOR-swizzled chunk layout (0 bank conflicts, R2-verified)
__device__ __forceinline__ int swz_off(int row, int quad) {
    return row * 32 + ((quad ^ ((row >> 1) & 3)) << 3);
}

// ---------------------------------------------------------------------------
// Fused weight prep: all 4 matrices of one layer, transposed W[K][N]->Wt[N][K]
// + fp32->bf16. 6912 blocks, branch is block-uniform.
__global__ __launch_bounds__(256)
void wprep_k(const float* __restrict__ Wqkv, const float* __restrict__ Wo,
             const float* __restrict__ W1, const float* __restrict__ W2,
             unsigned short* __restrict__ qkvT, unsigned short* __restrict__ woT,
             unsigned short* __restrict__ w1T, unsigned short* __restrict__ w2T) {
    __shared__ float tile[32][33];
    int bid = blockIdx.x;
    const float* W; unsigned short* Wt; int K, N, idx;
    if (bid < 1728)      { W = Wqkv; Wt = qkvT; K = 768;  N = 2304; idx = bid; }
    else if (bid < 2304) { W = Wo;   Wt = woT;  K = 768;  N = 768;  idx = bid - 1728; }
    else if (bid < 4608) { W = W1;   Wt = w1T;  K = 768;  N = 3072; idx = bid - 2304; }
    else                 { W = W2;   Wt = w2T;  K = 3072; N = 768;  idx = bid - 4608; }
    int ntile = N / 32;
    int n0 = (idx % ntile) * 32, k0 = (idx / ntile) * 32;
    int tx = threadIdx.x & 31, ty = threadIdx.x >> 5;
#pragma unroll
    for (int i = 0; i < 4; ++i) {
        int k = ty + i * 8;
        tile[k][tx] = W[(size_t)(k0 + k) * N + n0 + tx];
    }
    __syncthreads();
#pragma unroll
    for (int i = 0; i < 4; ++i) {
        int n = ty + i * 8;
        Wt[(size_t)(n0 + n) * K + k0 + tx] = f2bf(tile[tx][n]);
    }
}

// ---------------------------------------------------------------------------
__global__ __launch_bounds__(256)
void posenc_k(const float* __restrict__ x, float* __restrict__ h,
              unsigned short* __restrict__ hb) {
    int idx = blockIdx.x * 256 + threadIdx.x;
    const int TOT = 4 * 1024 * 768;
    if (idx >= TOT) return;
    int d = idx % 768;
    int s = (idx / 768) % 1024;
    int i2 = d >> 1;
    float dv = expf(-(float)(2 * i2) * (9.210340371976184f / 768.0f));
    float ang = (float)s * dv;
    float pe = (d & 1) ? cosf(ang) : sinf(ang);
    float v = x[idx] + pe;
    h[idx] = v;
    hb[idx] = f2bf(v);
}

// ---------------------------------------------------------------------------
// GEMM: C[M,N] = A[M,K](bf16) @ Bt[N,K](bf16)^T (+bias) (+relu), split-K via z.
// Output bf16. Single-barrier double-buffered global_load_lds staging.
template<int RELU, int BIAS>
__global__ __launch_bounds__(256)
void gemm_k(const unsigned short* __restrict__ A, const unsigned short* __restrict__ Bt,
            const float* __restrict__ bias, unsigned short* __restrict__ Cb,
            int M, int N, int K, int Kc) {
    __shared__ unsigned short As[2][128 * 32];
    __shared__ unsigned short Bs[2][128 * 32];
    const int tid = threadIdx.x;
    const int lane = tid & 63, wave = tid >> 6;
    const int l15 = lane & 15, quad = lane >> 4;
    const int m0 = blockIdx.y * 128, n0 = blockIdx.x * 128;
    const int wr = (wave >> 1) * 64, wc = (wave & 1) * 64;
    const int kstart = blockIdx.z * Kc;
    unsigned short* Cbp = Cb + (size_t)blockIdx.z * M * N;

    const int r0 = wave * 32 + (lane >> 2);
    const int kc0 = lane & 3;

    auto stage = [&](int k0, int bi) {
#pragma unroll
        for (int j = 0; j < 2; ++j) {
            int r = r0 + j * 16;
            int kcl = kc0 ^ ((r >> 1) & 3);
            gload_lds16(A + (size_t)(m0 + r) * K + k0 + kcl * 8,
                        &As[bi][(wave * 32 + j * 16) * 32]);
            gload_lds16(Bt + (size_t)(n0 + r) * K + k0 + kcl * 8,
                        &Bs[bi][(wave * 32 + j * 16) * 32]);
        }
    };

    f32x4 acc[4][4];
#pragma unroll
    for (int i = 0; i < 4; ++i)
#pragma unroll
        for (int j = 0; j < 4; ++j) acc[i][j] = (f32x4){0.f, 0.f, 0.f, 0.f};

    stage(kstart, 0);
    const int nk = Kc / 32;
    for (int t = 0; t < nk; ++t) {
        __syncthreads();
        if (t + 1 < nk) stage(kstart + (t + 1) * 32, (t + 1) & 1);
        const unsigned short* Asb = As[t & 1];
        const unsigned short* Bsb = Bs[t & 1];
        bf16x8 af[4], bfr[4];
#pragma unroll
        for (int mt = 0; mt < 4; ++mt)
            af[mt] = ld8(&Asb[swz_off(wr + mt * 16 + l15, quad)]);
#pragma unroll
        for (int nt = 0; nt < 4; ++nt)
            bfr[nt] = ld8(&Bsb[swz_off(wc + nt * 16 + l15, quad)]);
#pragma unroll
        for (int mt = 0; mt < 4; ++mt)
#pragma unroll
            for (int nt = 0; nt < 4; ++nt)
                acc[mt][nt] = __builtin_amdgcn_mfma_f32_16x16x32_bf16(
                    af[mt], bfr[nt], acc[mt][nt], 0, 0, 0);
    }
#pragma unroll
    for (int mt = 0; mt < 4; ++mt)
#pragma unroll
        for (int nt = 0; nt < 4; ++nt)
#pragma unroll
            for (int r = 0; r < 4; ++r) {
                int row = m0 + wr + mt * 16 + quad * 4 + r;
                int col = n0 + wc + nt * 16 + l15;
                float v = acc[mt][nt][r];
                if (BIAS) v += bias[col];
                if (RELU) v = fmaxf(v, 0.f);
                Cbp[(size_t)row * N + col] = f2bf(v);
            }
}

// ---------------------------------------------------------------------------
// Fused qkv prep: Q (scaled by 0.125*log2(e) for exp2 softmax), K copy,
// V transpose -> Vt[B,H,64(d),1024(s)]. grid (S/64, B*H), 256 threads.
__global__ __launch_bounds__(256)
void qkv_prep(const unsigned short* __restrict__ qkv, unsigned short* __restrict__ Q,
              unsigned short* __restrict__ Ko, unsigned short* __restrict__ Vt) {
    __shared__ unsigned short t[64][65];
    int bh = blockIdx.y, s0 = blockIdx.x * 64;
    int b = bh / 12, h = bh % 12;
    int tid = threadIdx.x;
    int tx = tid & 63, ty = tid >> 6;
#pragma unroll
    for (int r = 0; r < 16; ++r) {
        int i = ty + r * 4;
        t[i][tx] = qkv[(size_t)(b * 1024 + s0 + i) * 2304 + 1536 + h * 64 + tx];
    }
    const float QS = 0.18033688088889765f;  // 0.125 * log2(e)
#pragma unroll
    for (int it = 0; it < 2; ++it) {
        int task = tid + it * 256;
        int row = task >> 3, ch = (task & 7) * 8;
        size_t src = (size_t)(b * 1024 + s0 + row) * 2304 + h * 64 + ch;
        u16x8 qv = *(const u16x8*)&qkv[src];
#pragma unroll
        for (int j = 0; j < 8; ++j) qv[j] = f2bf(bf2f(qv[j]) * QS);
        *(u16x8*)&Q[((size_t)bh * 1024 + s0 + row) * 64 + ch] = qv;
        u16x8 kv = *(const u16x8*)&qkv[src + 768];
        *(u16x8*)&Ko[((size_t)bh * 1024 + s0 + row) * 64 + ch] = kv;
    }
    __syncthreads();
#pragma unroll
    for (int r = 0; r < 16; ++r) {
        int dd = ty + r * 4;
        Vt[((size_t)bh * 64 + dd) * 1024 + s0 + tx] = t[tx][dd];
    }
}

// ---------------------------------------------------------------------------
// Flash attention, fixed-max exp2 softmax, split-S=2 (pure sums).
// Writes bf16 numerator partials O2[z] and fp32 lsum ls[z]; combine divides.
// LDS 24576 B: Qs(4096 shorts, aliased by Ps after Q-frag hoist) + Ks + Vs.
__global__ __launch_bounds__(256)
void flash_k(const unsigned short* __restrict__ Q, const unsigned short* __restrict__ K,
             const unsigned short* __restrict__ Vt, unsigned short* __restrict__ O2,
             float* __restrict__ ls) {
    const int S = 1024, HD = 64;
    int bh = blockIdx.y, b = bh / 12, h = bh % 12;
    int q0 = blockIdx.x * 64;
    int zz = blockIdx.z;
    const unsigned short* Qp = Q + ((size_t)bh * S + q0) * HD;
    const unsigned short* Kp = K + (size_t)bh * S * HD;
    const unsigned short* Vp = Vt + (size_t)bh * HD * S;

    __shared__ unsigned short sm[12288];     // 24576 B
    unsigned short* Qs = sm;                  // [0,4096) also Ps
    unsigned short* Ks = sm + 4096;
    unsigned short* Vs = sm + 8192;

    int tid = threadIdx.x, lane = tid & 63, wave = tid >> 6;
    int l15 = lane & 15, quad = lane >> 4;
    const int rl0 = lane >> 2, c0 = lane & 3;

    // stage Q once (row R = khalf*64 + qrow)
#pragma unroll
    for (int j = 0; j < 2; ++j) {
        int R = wave * 32 + j * 16 + rl0;
        int khalf = R >> 6, grow = R & 63;
        int lch = c0 ^ ((R >> 1) & 3);
        gload_lds16(Qp + grow * HD + khalf * 32 + lch * 8,
                    &Qs[(wave * 32 + j * 16) * 32]);
    }
    __syncthreads();
    bf16x8 qa0 = ld8(&Qs[swz_off(wave * 16 + l15, quad)]);
    bf16x8 qa1 = ld8(&Qs[swz_off(64 + wave * 16 + l15, quad)]);

    f32x4 o[4];
#pragma unroll
    for (int i = 0; i < 4; ++i) o[i] = (f32x4){0.f, 0.f, 0.f, 0.f};
    f32x4 lacc = (f32x4){0.f, 0.f, 0.f, 0.f};
    bf16x8 ones;
    {
        union { u16x8 u; bf16x8 b; } c;
#pragma unroll
        for (int j = 0; j < 8; ++j) c.u[j] = 0x3F80;  // bf16 1.0
        ones = c.b;
    }
    unsigned short* Pw = sm + wave * 1024;   // 16 rows x 64, quad-XOR swizzled

    for (int kt = zz * 8; kt < zz * 8 + 8; ++kt) {
        __syncthreads();   // prev LDS reads (and prologue Q-frag reads) done
#pragma unroll
        for (int j = 0; j < 2; ++j) {
            int R = wave * 32 + j * 16 + rl0;
            int khalf = R >> 6, grow = R & 63;
            int lch = c0 ^ ((R >> 1) & 3);
            gload_lds16(Kp + (kt * 64 + grow) * HD + khalf * 32 + lch * 8,
                        &Ks[(wave * 32 + j * 16) * 32]);
            gload_lds16(Vp + (size_t)grow * S + kt * 64 + khalf * 32 + lch * 8,
                        &Vs[(wave * 32 + j * 16) * 32]);
        }
        __syncthreads();

        f32x4 sc[4];
#pragma unroll
        for (int cb = 0; cb < 4; ++cb) {
            bf16x8 kb0 = ld8(&Ks[swz_off(cb * 16 + l15, quad)]);
            bf16x8 kb1 = ld8(&Ks[swz_off(64 + cb * 16 + l15, quad)]);
            f32x4 z = (f32x4){0.f, 0.f, 0.f, 0.f};
            z = __builtin_amdgcn_mfma_f32_16x16x32_bf16(qa0, kb0, z, 0, 0, 0);
            z = __builtin_amdgcn_mfma_f32_16x16x32_bf16(qa1, kb1, z, 0, 0, 0);
            sc[cb] = z;
        }
        // exp2 (log2e folded into Q scale), truncate to bf16, store to Ps
#pragma unroll
        for (int cb = 0; cb < 4; ++cb)
#pragma unroll
            for (int r = 0; r < 4; ++r)
                Pw[(quad * 4 + r) * 64 + ((cb * 16 + l15) ^ (quad << 4))] =
                    f2bft(__builtin_amdgcn_exp2f(sc[cb][r]));
        bf16x8 pa0 = ld8(&Pw[l15 * 64 + ((quad * 8) ^ ((l15 >> 2) << 4))]);
        bf16x8 pa1 = ld8(&Pw[l15 * 64 + ((32 + quad * 8) ^ ((l15 >> 2) << 4))]);
        lacc = __builtin_amdgcn_mfma_f32_16x16x32_bf16(pa0, ones, lacc, 0, 0, 0);
        lacc = __builtin_amdgcn_mfma_f32_16x16x32_bf16(pa1, ones, lacc, 0, 0, 0);
#pragma unroll
        for (int cb = 0; cb < 4; ++cb) {
            bf16x8 vb0 = ld8(&Vs[swz_off(cb * 16 + l15, quad)]);
            bf16x8 vb1 = ld8(&Vs[swz_off(64 + cb * 16 + l15, quad)]);
            o[cb] = __builtin_amdgcn_mfma_f32_16x16x32_bf16(pa0, vb0, o[cb], 0, 0, 0);
            o[cb] = __builtin_amdgcn_mfma_f32_16x16x32_bf16(pa1, vb1, o[cb], 0, 0, 0);
        }
    }
    unsigned short* Op = O2 + (size_t)zz * 4096 * 768;
#pragma unroll
    for (int cb = 0; cb < 4; ++cb)
#pragma unroll
        for (int r = 0; r < 4; ++r) {
            int row = q0 + wave * 16 + quad * 4 + r;
            Op[((size_t)(b * 1024 + row)) * 768 + h * 64 + cb * 16 + l15] =
                f2bf(o[cb][r]);
        }
    if (l15 == 0) {
#pragma unroll
        for (int r = 0; r < 4; ++r)
            ls[zz * 49152 + bh * 1024 + q0 + wave * 16 + quad * 4 + r] = lacc[r];
    }
}

// ---------------------------------------------------------------------------
// Combine split-S halves: ctx = (O0 + O1) / (l0 + l1). 1536 blocks.
__global__ __launch_bounds__(256)
void attn_combine_k(const unsigned short* __restrict__ O2, const float* __restrict__ ls,
                    unsigned short* __restrict__ ctx) {
    int idx = blockIdx.x * 256 + threadIdx.x;   // u16x8 chunks: 4096*96
    int ch = idx % 96;
    int row = idx / 96;
    int col = ch * 8;
    int b = row >> 10, s = row & 1023, h = col >> 6;
    const size_t MD = (size_t)4096 * 768;
    u16x8 o0 = *(const u16x8*)&O2[(size_t)row * 768 + col];
    u16x8 o1 = *(const u16x8*)&O2[MD + (size_t)row * 768 + col];
    int li = (b * 12 + h) * 1024 + s;
    float rl = 1.0f / (ls[li] + ls[49152 + li]);
    u16x8 ov;
#pragma unroll
    for (int j = 0; j < 8; ++j)
        ov[j] = f2bf((bf2f(o0[j]) + bf2f(o1[j])) * rl);
    *(u16x8*)&ctx[(size_t)row * 768 + col] = ov;
}

// ---------------------------------------------------------------------------
// LayerNorm over D=768. NPART>0: residual = X + sum(bf16 partials) + proj-bias.
template<int NPART, int WBF16>
__global__ __launch_bounds__(256)
void ln_k(const float* __restrict__ X, const unsigned short* __restrict__ P,
          const float* __restrict__ pb,
          const float* __restrict__ g, const float* __restrict__ bta,
          float* __restrict__ Yf, unsigned short* __restrict__ Yb) {
    const int D = 768;
    const size_t MD = (size_t)4096 * 768;
    int row = blockIdx.x;
    int tid = threadIdx.x;
    const float* x = X + (size_t)row * D;
    float v[3];
    float s = 0.f, s2 = 0.f;
#pragma unroll
    for (int i = 0; i < 3; ++i) {
        int c = i * 256 + tid;
        float t = x[c];
        if (NPART > 0) {
            float r = pb[c];
#pragma unroll
            for (int pi = 0; pi < NPART; ++pi)
                r += bf2f(P[MD * pi + (size_t)row * D + c]);
            t += r;
        }
        v[i] = t;
        s += t;
        s2 += t * t;
    }
#pragma unroll
    for (int off = 1; off < 64; off <<= 1) {
        s += __shfl_xor(s, off);
        s2 += __shfl_xor(s2, off);
    }
    __shared__ float rs[4], rs2[4];
    int wave = tid >> 6, lane = tid & 63;
    if (lane == 0) { rs[wave] = s; rs2[wave] = s2; }
    __syncthreads();
    s = rs[0] + rs[1] + rs[2] + rs[3];
    s2 = rs2[0] + rs2[1] + rs2[2] + rs2[3];
    float mu = s * (1.f / 768.f);
    float var = s2 * (1.f / 768.f) - mu * mu;
    float rstd = rsqrtf(var + 1e-5f);
#pragma unroll
    for (int i = 0; i < 3; ++i) {
        int c = i * 256 + tid;
        float y = (v[i] - mu) * rstd * g[c] + bta[c];
        Yf[(size_t)row * D + c] = y;
        if (WBF16) Yb[(size_t)row * D + c] = f2bf(y);
    }
}

// ---------------------------------------------------------------------------
extern "C" void kernel_launch(void* const* d_in, const int* in_sizes, int n_in,
                              void* d_out, int out_size, void* d_ws, size_t ws_size,
                              hipStream_t stream) {
    const float* x    = (const float*)d_in[0];
    const float* Wqkv = (const float*)d_in[1];
    const float* bqkv = (const float*)d_in[2];
    const float* Wo   = (const float*)d_in[3];
    const float* bo   = (const float*)d_in[4];
    const float* ln1g = (const float*)d_in[5];
    const float* ln1b = (const float*)d_in[6];
    const float* W1   = (const float*)d_in[7];
    const float* b1   = (const float*)d_in[8];
    const float* W2   = (const float*)d_in[9];
    const float* b2   = (const float*)d_in[10];
    const float* ln2g = (const float*)d_in[11];
    const float* ln2b = (const float*)d_in[12];
    const float* lnfg = (const float*)d_in[13];
    const float* lnfb = (const float*)d_in[14];

    const int B = 4, S = 1024, D = 768, H = 12, F = 3072, L = 6;
    const int M = B * S;  // 4096

    char* p = (char*)d_ws;
    auto alloc = [&](size_t bytes) -> char* {
        char* r = p;
        p += (bytes + 255) & ~(size_t)255;
        return r;
    };
    float* h             = (float*)alloc((size_t)M * D * 4);
    unsigned short* tmp  = (unsigned short*)alloc((size_t)4 * M * D * 2); // split-K partials / O2 partials
    float* lsbuf         = (float*)alloc((size_t)2 * 48 * 1024 * 4);
    unsigned short* hb   = (unsigned short*)alloc((size_t)M * D * 2);
    unsigned short* act  = (unsigned short*)alloc((size_t)M * F * 2); // qkv / ffn1 union
    unsigned short* Qb   = (unsigned short*)alloc((size_t)M * D * 2);
    unsigned short* Kb   = (unsigned short*)alloc((size_t)M * D * 2);
    unsigned short* Vtb  = (unsigned short*)alloc((size_t)M * D * 2);
    unsigned short* ctx  = (unsigned short*)alloc((size_t)M * D * 2);
    unsigned short* wqkvT = (unsigned short*)alloc((size_t)3 * D * D * 2);
    unsigned short* woT   = (unsigned short*)alloc((size_t)D * D * 2);
    unsigned short* w1T   = (unsigned short*)alloc((size_t)D * F * 2);
    unsigned short* w2T   = (unsigned short*)alloc((size_t)D * F * 2);
    unsigned short* qkvb = act;
    unsigned short* f1b  = act;

    posenc_k<<<(M * D) / 256, 256, 0, stream>>>(x, h, hb);

    for (int l = 0; l < L; ++l) {
        wprep_k<<<6912, 256, 0, stream>>>(
            Wqkv + (size_t)l * D * 3 * D, Wo + (size_t)l * D * D,
            W1 + (size_t)l * D * F, W2 + (size_t)l * F * D,
            wqkvT, woT, w1T, w2T);

        // qkv = hb @ WqkvT + bqkv (bf16)
        gemm_k<0, 1><<<dim3(3 * D / 128, M / 128, 1), 256, 0, stream>>>(
            hb, wqkvT, bqkv + (size_t)l * 3 * D, qkvb, M, 3 * D, D, D);
        qkv_prep<<<dim3(S / 64, B * H), 256, 0, stream>>>(qkvb, Qb, Kb, Vtb);
        flash_k<<<dim3(S / 64, B * H, 2), 256, 0, stream>>>(Qb, Kb, Vtb, tmp, lsbuf);
        attn_combine_k<<<(M * 96) / 256, 256, 0, stream>>>(tmp, lsbuf, ctx);
        // attn out proj: split-K=4, bf16 partials (no bias)
        gemm_k<0, 0><<<dim3(D / 128, M / 128, 4), 256, 0, stream>>>(
            ctx, woT, nullptr, tmp, M, D, D, D / 4);
        ln_k<4, 1><<<M, 256, 0, stream>>>(h, tmp, bo + (size_t)l * D,
                                          ln1g + (size_t)l * D, ln1b + (size_t)l * D,
                                          h, hb);
        // ffn1 (relu, bf16 out)
        gemm_k<1, 1><<<dim3(F / 128, M / 128, 1), 256, 0, stream>>>(
            hb, w1T, b1 + (size_t)l * F, f1b, M, F, D, D);
        // ffn2: split-K=4, bf16 partials (no bias)
        gemm_k<0, 0><<<dim3(D / 128, M / 128, 4), 256, 0, stream>>>(
            f1b, w2T, nullptr, tmp, M, D, F, F / 4);
        ln_k<4, 1><<<M, 256, 0, stream>>>(h, tmp, b2 + (size_t)l * D,
                                          ln2g + (size_t)l * D, ln2b + (size_t)l * D,
                                          h, hb);
    }
    ln_k<0, 0><<<M, 256, 0, stream>>>(h, nullptr, nullptr, lnfg, lnfb,
                                      (float*)d_out, nullptr);
}